// Round 9
// baseline (259.487 us; speedup 1.0000x reference)
//
#include <hip/hip_runtime.h>
#include <stdint.h>

// LinearAttention (literal listing, softmax over n):
//   ctx_h = softmax_n(K_h) @ V_h^T;  out = wout·(ctx^T ⊛ q) + b
//   collapsed: out[b] = Weff[b]@x[b]+b,  Weff = wout·blockdiag(ctx^T)·W_q
// ROUND 19: resubmit of round-18 (bench infra "container failed twice";
// same signature as round 4 which proved to be infra — identical kernel ran
// fine on resubmit. Audit: uniform barriers, const loop bounds, in-bounds
// addressing, ws 58MB<256MB, async-only memset. No container-killers.)
//  * R7: top-5 all poison fills (42us) -> k1w ~38-40, k3e ~20-25. k1 is
//    latency-bound at 3x its traffic floor; at 864 blocks the GRID caps
//    concurrency (3.375 blk/CU), at 1728 the 37.9KB LDS caps it (4 blk/CU).
//  * k1x: 1728 blocks x 4 tiles + SINGLE-buffer XT (2 barriers/iter):
//    LDS 37.9->29.2KB -> 5 blk/CU of independent chains (+48% streams).
//    (EKV must stay [32][40]: b128 needs 16B-aligned rows; XT [64][68]:
//    ushort4 writes need 8B-aligned rows.)
//  * Xbf: k1 mirrors its staged bf16 tiles to ws (28.3MB); k3f reads bf16
//    (FETCH halved, f2bf pass gone). Bit-identical to f2bf(x) in k3e.
//  * k2pre 54-summand (R6, proven), k2s unchanged, k3e kept for fallback.

using f32x4 = __attribute__((ext_vector_type(4))) float;
using s16x8 = __attribute__((ext_vector_type(8))) short;

#define NSP 110592  // 48*48*48
#define NSHADOW 16
#define MFMA(a, b, c) __builtin_amdgcn_mfma_f32_16x16x32_bf16((a), (b), (c), 0, 0, 0)

static __device__ __forceinline__ unsigned short f2bf(float f) {
    return (unsigned short)((__float_as_uint(f) + 0x8000u) >> 16);  // round-half-up
}

// ---------------------------------------------------------------------------
// k1x: 1728 blocks (864/batch), 4 contiguous 32-n tiles, SINGLE-buffer XT
// (2 barriers/iter, cross-tile prefetch in regs). Round-0 compute body.
// mode 0: per-block partial stores to Sp/Zp (+ bf16 x mirror to xbf).
// mode 1: 16-shadow atomics (small-ws fallback), xbf ignored.
// ---------------------------------------------------------------------------
__global__ __launch_bounds__(256, 5) void k1x(
    const float* __restrict__ x, const float* __restrict__ wqkv,
    float* __restrict__ Sdst, float* __restrict__ Zdst,
    unsigned short* __restrict__ xbf, int mode)
{
    __shared__ unsigned short XT[64][68];         // single staged x tile (bf16)
    __shared__ unsigned short EKV[4][2][32][40];  // wave-private [K/V][row][col]
    const int tid = threadIdx.x;
    const int wv = tid >> 6;
    const int l = tid & 63;
    const int l15 = l & 15, l4 = l >> 4;
    const int blk = blockIdx.x;
    const int b = blk / 864;            // 864 blocks/batch
    const int tbase = (blk % 864) * 4;  // 4 contiguous tiles
    const int h = wv;

    // A-frags: rows of W_k (128+h*32+m) / W_v (256+h*32+m); A[m=l15][k=l4*8+j]
    s16x8 afr[2][2][2];  // [kv][mtile][kstep]
    for (int kv = 0; kv < 2; ++kv)
        for (int mt = 0; mt < 2; ++mt)
            for (int s = 0; s < 2; ++s) {
                int row = 128 + kv * 128 + h * 32 + mt * 16 + l15;
                const float* wp = wqkv + row * 64 + s * 32 + l4 * 8;
                s16x8 a;
#pragma unroll
                for (int j = 0; j < 8; ++j) a[j] = (short)f2bf(wp[j]);
                afr[kv][mt][s] = a;
            }

    f32x4 sacc[2][2] = {};
    float zrow[8] = {};

    unsigned short (*EK)[40] = EKV[wv][0];
    unsigned short (*EV)[40] = EKV[wv][1];
    const float* xb = x + (size_t)b * 64 * NSP;
    unsigned short* xbfb = xbf ? xbf + (size_t)b * 64 * NSP : nullptr;

    // staging addresses for this thread (2 float4 per tile)
    const int c0 = tid >> 3;                        // p=0 row
    const int ng0 = (tid & 7) ^ (c0 & 7);
    const int c1 = (tid + 256) >> 3;                // p=1 row
    const int ng1 = ((tid + 256) & 7) ^ (c1 & 7);

    float4 g0, g1;
    {   // preload tile 0
        const int n0 = tbase * 32;
        g0 = *(const float4*)(xb + (size_t)c0 * NSP + n0 + 4 * ng0);
        g1 = *(const float4*)(xb + (size_t)c1 * NSP + n0 + 4 * ng1);
    }

    for (int it = 0; it < 4; ++it) {
        if (it > 0) __syncthreads();  // all waves done READING XT[it-1]
        // write staged regs -> XT (+ bf16 global mirror)
        {
            ushort4 u0, u1;
            u0.x = f2bf(g0.x); u0.y = f2bf(g0.y); u0.z = f2bf(g0.z); u0.w = f2bf(g0.w);
            u1.x = f2bf(g1.x); u1.y = f2bf(g1.y); u1.z = f2bf(g1.z); u1.w = f2bf(g1.w);
            *(ushort4*)&XT[c0][4 * ng0] = u0;
            *(ushort4*)&XT[c1][4 * ng1] = u1;
            if (xbfb) {
                const int n0c = (tbase + it) * 32;
                *(ushort4*)(xbfb + (size_t)c0 * NSP + n0c + 4 * ng0) = u0;
                *(ushort4*)(xbfb + (size_t)c1 * NSP + n0c + 4 * ng1) = u1;
            }
        }
        // issue next tile's loads; they fly across the barrier + compute
        if (it < 3) {
            const int n0 = (tbase + it + 1) * 32;
            g0 = *(const float4*)(xb + (size_t)c0 * NSP + n0 + 4 * ng0);
            g1 = *(const float4*)(xb + (size_t)c1 * NSP + n0 + 4 * ng1);
        }
        __syncthreads();              // XT writes visible

        // GEMM1: [K_h;V_h] = W @ xtile (M=64,K=64,N=32)
        f32x4 ck[2][2] = {}, cv[2][2] = {};
#pragma unroll
        for (int s = 0; s < 2; ++s)
#pragma unroll
            for (int nt = 0; nt < 2; ++nt) {
                s16x8 bfr;  // B[k=c][n]: n=l15, c=l4*8+j (+32s)
#pragma unroll
                for (int j = 0; j < 8; ++j)
                    bfr[j] = (short)XT[s * 32 + l4 * 8 + j][nt * 16 + l15];
#pragma unroll
                for (int mt = 0; mt < 2; ++mt) {
                    ck[mt][nt] = MFMA(afr[0][mt][s], bfr, ck[mt][nt]);
                    cv[mt][nt] = MFMA(afr[1][mt][s], bfr, cv[mt][nt]);
                }
            }
        // exp -> Z(regs) + EK; V -> EV   (C: row=mt*16+l4*4+r, col=nt*16+l15)
#pragma unroll
        for (int mt = 0; mt < 2; ++mt)
#pragma unroll
            for (int nt = 0; nt < 2; ++nt) {
                int col = nt * 16 + l15;
#pragma unroll
                for (int r = 0; r < 4; ++r) {
                    int row = mt * 16 + l4 * 4 + r;
                    float ek = __expf(ck[mt][nt][r]);
                    zrow[mt * 4 + r] += ek;
                    EK[row][col] = f2bf(ek);
                    EV[row][col] = f2bf(cv[mt][nt][r]);
                }
            }
        // GEMM2: S_h += expK(32x32) @ V^T (wave-private, in-order DS pipe)
#pragma unroll
        for (int td = 0; td < 2; ++td) {
            s16x8 a2 = *(const s16x8*)&EK[td * 16 + l15][l4 * 8];
#pragma unroll
            for (int te = 0; te < 2; ++te) {
                s16x8 b2 = *(const s16x8*)&EV[te * 16 + l15][l4 * 8];
                sacc[td][te] = MFMA(a2, b2, sacc[td][te]);
            }
        }
    }

    // Z: butterfly over the 16 replicating l15 lanes
#pragma unroll
    for (int i = 0; i < 8; ++i) {
        float z = zrow[i];
        z += __shfl_xor(z, 1);
        z += __shfl_xor(z, 2);
        z += __shfl_xor(z, 4);
        z += __shfl_xor(z, 8);
        zrow[i] = z;
    }

    if (mode == 0) {
        // per-block partial: plain stores, fully written, no zeroing needed
        float* Zb = Zdst + (size_t)blk * 128;
        if (l15 == 0)
#pragma unroll
            for (int mt = 0; mt < 2; ++mt)
#pragma unroll
                for (int r = 0; r < 4; ++r)
                    Zb[h * 32 + mt * 16 + l4 * 4 + r] = zrow[mt * 4 + r];
        float* Sb = Sdst + (size_t)blk * 4096 + h * 1024;
#pragma unroll
        for (int td = 0; td < 2; ++td)
#pragma unroll
            for (int te = 0; te < 2; ++te)
#pragma unroll
                for (int r = 0; r < 4; ++r)
                    Sb[(td * 16 + l4 * 4 + r) * 32 + te * 16 + l15] =
                        sacc[td][te][r];
    } else {
        const int shadow = blk & (NSHADOW - 1);
        float* Zb = Zdst + (size_t)(shadow * 2 + b) * 128;
        if (l15 == 0)
#pragma unroll
            for (int mt = 0; mt < 2; ++mt)
#pragma unroll
                for (int r = 0; r < 4; ++r)
                    atomicAdd(&Zb[h * 32 + mt * 16 + l4 * 4 + r], zrow[mt * 4 + r]);
        float* Sb = Sdst + (size_t)(shadow * 2 + b) * 4096 + h * 1024;
#pragma unroll
        for (int td = 0; td < 2; ++td)
#pragma unroll
            for (int te = 0; te < 2; ++te)
#pragma unroll
                for (int r = 0; r < 4; ++r)
                    atomicAdd(&Sb[(td * 16 + l4 * 4 + r) * 32 + te * 16 + l15],
                              sacc[td][te][r]);
    }
}

// ---------------------------------------------------------------------------
// k2pre: 128 blocks (16 groups x 2 batches x 4 quarter-rows) x 256 threads:
// sum 54 per-block partials (w = s + 16j) -> 16-intermediate layout for k2s.
// ---------------------------------------------------------------------------
__global__ __launch_bounds__(256) void k2pre(
    const float* __restrict__ Sp, const float* __restrict__ Zp,
    float* __restrict__ Ssh, float* __restrict__ Zsh)
{
    const int q = blockIdx.x & 3;
    const int b = (blockIdx.x >> 2) & 1;
    const int s = blockIdx.x >> 3;
    const int t = threadIdx.x;
    const int i = q * 1024 + t * 4;
    float4 acc = {0.f, 0.f, 0.f, 0.f};
#pragma unroll 6
    for (int j = 0; j < 54; ++j) {
        const float4 v =
            *(const float4*)&Sp[(size_t)(b * 864 + s + 16 * j) * 4096 + i];
        acc.x += v.x; acc.y += v.y; acc.z += v.z; acc.w += v.w;
    }
    *(float4*)&Ssh[(size_t)(s * 2 + b) * 4096 + i] = acc;
    if (q == 0 && t < 128) {
        float z = 0.f;
#pragma unroll 6
        for (int j = 0; j < 54; ++j)
            z += Zp[(size_t)(b * 864 + s + 16 * j) * 128 + t];
        Zsh[(size_t)(s * 2 + b) * 128 + t] = z;
    }
}

// ---------------------------------------------------------------------------
// k2s: sum 16 shadows -> ctx = S/Z; P[c][hd] = sum_e wout[c][h*32+e]*ctx[h][d][e];
//      Weff[c][c2] = sum_hd P[c][hd]*wqkv[hd][c2] -> bf16
// ---------------------------------------------------------------------------
__global__ __launch_bounds__(1024) void k2s(
    const float* __restrict__ Ssh, const float* __restrict__ Zsh,
    const float* __restrict__ wout, const float* __restrict__ wqkv,
    unsigned short* __restrict__ WE)
{
    __shared__ float ctx[4][32][32];
    __shared__ float P[64][128];
    __shared__ float Zl[128];
    const int b = blockIdx.x;
    const int t = threadIdx.x;
    if (t < 128) {
        float z = 0.f;
#pragma unroll
        for (int s = 0; s < NSHADOW; ++s) z += Zsh[(size_t)(s * 2 + b) * 128 + t];
        Zl[t] = z;
    }
    __syncthreads();
    for (int i = t; i < 4096; i += 1024) {
        float sv = 0.f;
#pragma unroll
        for (int s = 0; s < NSHADOW; ++s) sv += Ssh[(size_t)(s * 2 + b) * 4096 + i];
        int h = i >> 10, d = (i >> 5) & 31;
        ctx[h][d][i & 31] = sv / Zl[h * 32 + d];
    }
    __syncthreads();
    for (int i = t; i < 8192; i += 1024) {
        int c = i >> 7, hd = i & 127, h = hd >> 5, d = hd & 31;
        const float* wo = wout + c * 128 + h * 32;
        float acc = 0.f;
#pragma unroll 8
        for (int e = 0; e < 32; ++e) acc += wo[e] * ctx[h][d][e];
        P[c][hd] = acc;
    }
    __syncthreads();
    for (int i = t; i < 4096; i += 1024) {
        int c = i >> 6, c2 = i & 63;
        float acc = 0.f;
#pragma unroll 8
        for (int hd = 0; hd < 128; ++hd) acc += P[c][hd] * wqkv[hd * 64 + c2];
        WE[b * 4096 + c * 64 + c2] = f2bf(acc);
    }
}

// ---------------------------------------------------------------------------
// k3f: out[b] = Weff[b]@x[b] + bias. 1728 blocks x 128-col strips. LDS-free;
// B-frags read as bf16 DIRECTLY from Xbf (k1's mirror) — half the bytes of
// k3e and no f2bf pass. Direct global stores. No LDS, no barriers.
// ---------------------------------------------------------------------------
__global__ __launch_bounds__(256) void k3f(
    const unsigned short* __restrict__ xbf, const unsigned short* __restrict__ WE,
    const float* __restrict__ bout, float* __restrict__ out)
{
    const int tid = threadIdx.x;
    const int wv = tid >> 6;
    const int l = tid & 63;
    const int l15 = l & 15, l4 = l >> 4;
    const int b = blockIdx.x / 864;
    const int n0 = (blockIdx.x % 864) * 128;

    s16x8 afr[4][2];
#pragma unroll
    for (int mt = 0; mt < 4; ++mt)
#pragma unroll
        for (int s = 0; s < 2; ++s)
            afr[mt][s] = *(const s16x8*)(WE + b * 4096 + (mt * 16 + l15) * 64 + s * 32 + l4 * 8);

    float bias[4][4];
#pragma unroll
    for (int mt = 0; mt < 4; ++mt)
#pragma unroll
        for (int r = 0; r < 4; ++r) bias[mt][r] = bout[mt * 16 + l4 * 4 + r];

    const unsigned short* xbfb = xbf + (size_t)b * 64 * NSP;
    float* ob = out + (size_t)b * 64 * NSP;

    const int nq = wv * 32;
    // lane's gather base: row l4*8, col n0+nq+l15
    const unsigned short* xq = xbfb + (size_t)(l4 * 8) * NSP + n0 + nq + l15;

    f32x4 acc[4][2] = {};
#pragma unroll
    for (int s = 0; s < 2; ++s) {
        // load 16 bf16: rows s*32+l4*8+j, cols {0,16}
        s16x8 b0, b1;  // B[k=s*32+l4*8+j][n=nt*16+l15]
#pragma unroll
        for (int j = 0; j < 8; ++j) {
            const unsigned short* p = xq + (size_t)(s * 32 + j) * NSP;
            b0[j] = (short)p[0];
            b1[j] = (short)p[16];
        }
#pragma unroll
        for (int mt = 0; mt < 4; ++mt) {
            acc[mt][0] = MFMA(afr[mt][s], b0, acc[mt][0]);
            acc[mt][1] = MFMA(afr[mt][s], b1, acc[mt][1]);
        }
    }

    // direct stores: for fixed (mt,nt,r) the wave writes 4 rows x 16
    // consecutive floats = 4 fully-utilized 64B segments.
#pragma unroll
    for (int mt = 0; mt < 4; ++mt)
#pragma unroll
        for (int nt = 0; nt < 2; ++nt)
#pragma unroll
            for (int r = 0; r < 4; ++r)
                ob[(size_t)(mt * 16 + l4 * 4 + r) * NSP + n0 + nq + nt * 16 + l15] =
                    acc[mt][nt][r] + bias[mt][r];
}

// ---------------------------------------------------------------------------
// k3e (fallback, small-ws path): identical to k3f but gathers fp32 x + f2bf.
// ---------------------------------------------------------------------------
__global__ __launch_bounds__(256) void k3e(
    const float* __restrict__ x, const unsigned short* __restrict__ WE,
    const float* __restrict__ bout, float* __restrict__ out)
{
    const int tid = threadIdx.x;
    const int wv = tid >> 6;
    const int l = tid & 63;
    const int l15 = l & 15, l4 = l >> 4;
    const int b = blockIdx.x / 864;
    const int n0 = (blockIdx.x % 864) * 128;

    s16x8 afr[4][2];
#pragma unroll
    for (int mt = 0; mt < 4; ++mt)
#pragma unroll
        for (int s = 0; s < 2; ++s)
            afr[mt][s] = *(const s16x8*)(WE + b * 4096 + (mt * 16 + l15) * 64 + s * 32 + l4 * 8);

    float bias[4][4];
#pragma unroll
    for (int mt = 0; mt < 4; ++mt)
#pragma unroll
        for (int r = 0; r < 4; ++r) bias[mt][r] = bout[mt * 16 + l4 * 4 + r];

    const float* xb = x + (size_t)b * 64 * NSP;
    float* ob = out + (size_t)b * 64 * NSP;

    const int nq = wv * 32;
    const float* xq = xb + (size_t)(l4 * 8) * NSP + n0 + nq + l15;

    f32x4 acc[4][2] = {};
#pragma unroll
    for (int s = 0; s < 2; ++s) {
        float t0[8], t1[8];
#pragma unroll
        for (int j = 0; j < 8; ++j) {
            const float* p = xq + (size_t)(s * 32 + j) * NSP;
            t0[j] = p[0];
            t1[j] = p[16];
        }
        s16x8 b0, b1;
#pragma unroll
        for (int j = 0; j < 8; ++j) {
            b0[j] = (short)f2bf(t0[j]);
            b1[j] = (short)f2bf(t1[j]);
        }
#pragma unroll
        for (int mt = 0; mt < 4; ++mt) {
            acc[mt][0] = MFMA(afr[mt][s], b0, acc[mt][0]);
            acc[mt][1] = MFMA(afr[mt][s], b1, acc[mt][1]);
        }
    }

#pragma unroll
    for (int mt = 0; mt < 4; ++mt)
#pragma unroll
        for (int nt = 0; nt < 2; ++nt)
#pragma unroll
            for (int r = 0; r < 4; ++r)
                ob[(size_t)(mt * 16 + l4 * 4 + r) * NSP + n0 + nq + nt * 16 + l15] =
                    acc[mt][nt][r] + bias[mt][r];
}

extern "C" void kernel_launch(void* const* d_in, const int* in_sizes, int n_in,
                              void* d_out, int out_size, void* d_ws, size_t ws_size,
                              hipStream_t stream) {
    // Inputs by size (order-proof): x=14155776, w_qkv=24576, w_out=8192, b_out=64.
    const float *x = nullptr, *wqkv = nullptr, *wout = nullptr, *bout = nullptr;
    for (int i = 0; i < n_in; ++i) {
        if (in_sizes[i] == 2 * 64 * NSP) x = (const float*)d_in[i];
        else if (in_sizes[i] == 384 * 64) wqkv = (const float*)d_in[i];
        else if (in_sizes[i] == 64 * 128) wout = (const float*)d_in[i];
        else if (in_sizes[i] == 64) bout = (const float*)d_in[i];
    }
    if (!x) x = (const float*)d_in[0];
    if (!wqkv) wqkv = (const float*)d_in[1];
    if (!wout) wout = (const float*)d_in[2];
    if (!bout) bout = (const float*)d_in[3];
    float* out = (float*)d_out;

    // big path layout:
    //   Sp fp32[1728][4096]   @0              (28311552 B)
    //   Zp fp32[1728][128]    @28311552       (884736 B)
    //   Ssh fp32[16][2][4096] @29196288       (524288 B)
    //   Zsh fp32[16][2][128]  @29720576       (16384 B)
    //   WE bf16[2][4096]      @29736960       (16384 B)
    //   Xbf bf16[2][64][NSP]  @29753344       (28311552 B)   end: 58064896
    // small path (fallback): Ssh @0, Zsh @524288, WE @540672 (atomics)
    const size_t NEED_BIG = 58064896;
    if (ws_size >= NEED_BIG) {
        float* Sp = (float*)d_ws;
        float* Zp = (float*)((char*)d_ws + 28311552);
        float* Ssh = (float*)((char*)d_ws + 29196288);
        float* Zsh = (float*)((char*)d_ws + 29720576);
        unsigned short* WE = (unsigned short*)((char*)d_ws + 29736960);
        unsigned short* Xbf = (unsigned short*)((char*)d_ws + 29753344);
        hipLaunchKernelGGL(k1x, dim3(1728), dim3(256), 0, stream, x, wqkv, Sp, Zp, Xbf, 0);
        hipLaunchKernelGGL(k2pre, dim3(128), dim3(256), 0, stream, Sp, Zp, Ssh, Zsh);
        hipLaunchKernelGGL(k2s, dim3(2), dim3(1024), 0, stream, Ssh, Zsh, wout, wqkv, WE);
        hipLaunchKernelGGL(k3f, dim3(1728), dim3(256), 0, stream, Xbf, WE, bout, out);
    } else {
        float* Ssh = (float*)d_ws;
        float* Zsh = (float*)((char*)d_ws + 524288);
        unsigned short* WE = (unsigned short*)((char*)d_ws + 540672);
        hipMemsetAsync(d_ws, 0, 540672, stream);  // zero shadows
        hipLaunchKernelGGL(k1x, dim3(1728), dim3(256), 0, stream, x, wqkv, Ssh, Zsh,
                           (unsigned short*)nullptr, 1);
        hipLaunchKernelGGL(k2s, dim3(2), dim3(1024), 0, stream, Ssh, Zsh, wout, wqkv, WE);
        hipLaunchKernelGGL(k3e, dim3(1728), dim3(256), 0, stream, x, WE, bout, out);
    }
}

// Round 10
// 184.818 us; speedup vs baseline: 1.4040x; 1.4040x over previous
//
#include <hip/hip_runtime.h>
#include <stdint.h>

// LinearAttention (literal listing, softmax over n):
//   ctx_h = softmax_n(K_h) @ V_h^T;  out = wout·(ctx^T ⊛ q) + b
//   collapsed: out[b] = Weff[b]@x[b]+b,  Weff = wout·blockdiag(ctx^T)·W_q
// ROUND 20: revert R9's k1x (VGPR 48 = spill; 3rd occurrence of the <60-VGPR
// spill signature; FETCH/WRITE +53/+86MB scratch). Base = R7 (best passing,
// 175.4us: k1w 864x8 dbuf lb(256,4) ~39us, k3e ~30us). ONE delta:
//  * k1y = k1w + Xbf bf16 mirror (2 ushort4 stores of already-computed
//    values; no restructure, no launch-bound change; VGPR watch: <60 => spill).
//  * k3f reads bf16 from Xbf: FETCH 56.6->28.3MB, f2bf pass gone. Bit-
//    identical numerics (same f2bf bits k3e computed inline).
// Fixed harness overhead ~84us/iter (two 268MB ws-poison fills).

using f32x4 = __attribute__((ext_vector_type(4))) float;
using s16x8 = __attribute__((ext_vector_type(8))) short;

#define NSP 110592  // 48*48*48
#define NSHADOW 16
#define MFMA(a, b, c) __builtin_amdgcn_mfma_f32_16x16x32_bf16((a), (b), (c), 0, 0, 0)

static __device__ __forceinline__ unsigned short f2bf(float f) {
    return (unsigned short)((__float_as_uint(f) + 0x8000u) >> 16);  // round-half-up
}

// ---------------------------------------------------------------------------
// k1y: 864 blocks (432/batch), 8 contiguous 32-n tiles, software-pipelined
// (dbuf XT, 1 barrier/iter, cross-tile prefetch). Round-0 compute body.
// mode 0: per-block partial stores to Sp/Zp + bf16 x mirror to xbf.
// mode 1: 16-shadow atomics (small-ws fallback), xbf ignored.
// ---------------------------------------------------------------------------
__global__ __launch_bounds__(256, 4) void k1y(
    const float* __restrict__ x, const float* __restrict__ wqkv,
    float* __restrict__ Sdst, float* __restrict__ Zdst,
    unsigned short* __restrict__ xbf, int mode)
{
    __shared__ unsigned short XT[2][64][68];      // dbuf staged x tile (bf16)
    __shared__ unsigned short EKV[4][2][32][40];  // wave-private [K/V][row][col]
    const int tid = threadIdx.x;
    const int wv = tid >> 6;
    const int l = tid & 63;
    const int l15 = l & 15, l4 = l >> 4;
    const int blk = blockIdx.x;
    const int b = blk / 432;            // 432 blocks/batch
    const int tbase = (blk % 432) * 8;  // 8 contiguous tiles
    const int h = wv;

    // A-frags: rows of W_k (128+h*32+m) / W_v (256+h*32+m); A[m=l15][k=l4*8+j]
    s16x8 afr[2][2][2];  // [kv][mtile][kstep]
    for (int kv = 0; kv < 2; ++kv)
        for (int mt = 0; mt < 2; ++mt)
            for (int s = 0; s < 2; ++s) {
                int row = 128 + kv * 128 + h * 32 + mt * 16 + l15;
                const float* wp = wqkv + row * 64 + s * 32 + l4 * 8;
                s16x8 a;
#pragma unroll
                for (int j = 0; j < 8; ++j) a[j] = (short)f2bf(wp[j]);
                afr[kv][mt][s] = a;
            }

    f32x4 sacc[2][2] = {};
    float zrow[8] = {};

    unsigned short (*EK)[40] = EKV[wv][0];
    unsigned short (*EV)[40] = EKV[wv][1];
    const float* xb = x + (size_t)b * 64 * NSP;
    unsigned short* xbfb = xbf ? xbf + (size_t)b * 64 * NSP : nullptr;

    // staging addresses for this thread (2 float4 per tile)
    const int c0 = tid >> 3;                        // p=0 row
    const int ng0 = (tid & 7) ^ (c0 & 7);
    const int c1 = (tid + 256) >> 3;                // p=1 row
    const int ng1 = ((tid + 256) & 7) ^ (c1 & 7);

    float4 g0, g1;
    {   // preload tile 0
        const int n0 = tbase * 32;
        g0 = *(const float4*)(xb + (size_t)c0 * NSP + n0 + 4 * ng0);
        g1 = *(const float4*)(xb + (size_t)c1 * NSP + n0 + 4 * ng1);
    }

    for (int it = 0; it < 8; ++it) {
        unsigned short (*XB)[68] = XT[it & 1];
        // write staged regs -> XT[buf] (+ bf16 global mirror)
        {
            ushort4 u0, u1;
            u0.x = f2bf(g0.x); u0.y = f2bf(g0.y); u0.z = f2bf(g0.z); u0.w = f2bf(g0.w);
            u1.x = f2bf(g1.x); u1.y = f2bf(g1.y); u1.z = f2bf(g1.z); u1.w = f2bf(g1.w);
            *(ushort4*)&XB[c0][4 * ng0] = u0;
            *(ushort4*)&XB[c1][4 * ng1] = u1;
            if (xbfb) {
                const int n0c = (tbase + it) * 32;
                *(ushort4*)(xbfb + (size_t)c0 * NSP + n0c + 4 * ng0) = u0;
                *(ushort4*)(xbfb + (size_t)c1 * NSP + n0c + 4 * ng1) = u1;
            }
        }
        // issue next tile's loads; they fly across the barrier + compute
        if (it < 7) {
            const int n0 = (tbase + it + 1) * 32;
            g0 = *(const float4*)(xb + (size_t)c0 * NSP + n0 + 4 * ng0);
            g1 = *(const float4*)(xb + (size_t)c1 * NSP + n0 + 4 * ng1);
        }
        __syncthreads();

        // GEMM1: [K_h;V_h] = W @ xtile (M=64,K=64,N=32)
        f32x4 ck[2][2] = {}, cv[2][2] = {};
#pragma unroll
        for (int s = 0; s < 2; ++s)
#pragma unroll
            for (int nt = 0; nt < 2; ++nt) {
                s16x8 bfr;  // B[k=c][n]: n=l15, c=l4*8+j (+32s)
#pragma unroll
                for (int j = 0; j < 8; ++j)
                    bfr[j] = (short)XB[s * 32 + l4 * 8 + j][nt * 16 + l15];
#pragma unroll
                for (int mt = 0; mt < 2; ++mt) {
                    ck[mt][nt] = MFMA(afr[0][mt][s], bfr, ck[mt][nt]);
                    cv[mt][nt] = MFMA(afr[1][mt][s], bfr, cv[mt][nt]);
                }
            }
        // exp -> Z(regs) + EK; V -> EV   (C: row=mt*16+l4*4+r, col=nt*16+l15)
#pragma unroll
        for (int mt = 0; mt < 2; ++mt)
#pragma unroll
            for (int nt = 0; nt < 2; ++nt) {
                int col = nt * 16 + l15;
#pragma unroll
                for (int r = 0; r < 4; ++r) {
                    int row = mt * 16 + l4 * 4 + r;
                    float ek = __expf(ck[mt][nt][r]);
                    zrow[mt * 4 + r] += ek;
                    EK[row][col] = f2bf(ek);
                    EV[row][col] = f2bf(cv[mt][nt][r]);
                }
            }
        // GEMM2: S_h += expK(32x32) @ V^T (wave-private, in-order DS pipe)
#pragma unroll
        for (int td = 0; td < 2; ++td) {
            s16x8 a2 = *(const s16x8*)&EK[td * 16 + l15][l4 * 8];
#pragma unroll
            for (int te = 0; te < 2; ++te) {
                s16x8 b2 = *(const s16x8*)&EV[te * 16 + l15][l4 * 8];
                sacc[td][te] = MFMA(a2, b2, sacc[td][te]);
            }
        }
        // no second barrier: next iter writes the other XT buffer
    }

    // Z: butterfly over the 16 replicating l15 lanes
#pragma unroll
    for (int i = 0; i < 8; ++i) {
        float z = zrow[i];
        z += __shfl_xor(z, 1);
        z += __shfl_xor(z, 2);
        z += __shfl_xor(z, 4);
        z += __shfl_xor(z, 8);
        zrow[i] = z;
    }

    if (mode == 0) {
        // per-block partial: plain stores, fully written, no zeroing needed
        float* Zb = Zdst + (size_t)blk * 128;
        if (l15 == 0)
#pragma unroll
            for (int mt = 0; mt < 2; ++mt)
#pragma unroll
                for (int r = 0; r < 4; ++r)
                    Zb[h * 32 + mt * 16 + l4 * 4 + r] = zrow[mt * 4 + r];
        float* Sb = Sdst + (size_t)blk * 4096 + h * 1024;
#pragma unroll
        for (int td = 0; td < 2; ++td)
#pragma unroll
            for (int te = 0; te < 2; ++te)
#pragma unroll
                for (int r = 0; r < 4; ++r)
                    Sb[(td * 16 + l4 * 4 + r) * 32 + te * 16 + l15] =
                        sacc[td][te][r];
    } else {
        const int shadow = blk & (NSHADOW - 1);
        float* Zb = Zdst + (size_t)(shadow * 2 + b) * 128;
        if (l15 == 0)
#pragma unroll
            for (int mt = 0; mt < 2; ++mt)
#pragma unroll
                for (int r = 0; r < 4; ++r)
                    atomicAdd(&Zb[h * 32 + mt * 16 + l4 * 4 + r], zrow[mt * 4 + r]);
        float* Sb = Sdst + (size_t)(shadow * 2 + b) * 4096 + h * 1024;
#pragma unroll
        for (int td = 0; td < 2; ++td)
#pragma unroll
            for (int te = 0; te < 2; ++te)
#pragma unroll
                for (int r = 0; r < 4; ++r)
                    atomicAdd(&Sb[(td * 16 + l4 * 4 + r) * 32 + te * 16 + l15],
                              sacc[td][te][r]);
    }
}

// ---------------------------------------------------------------------------
// k2pre: 128 blocks (16 groups x 2 batches x 4 quarter-rows) x 256 threads:
// sum 27 per-block partials (w = s + 16j) -> 16-intermediate layout for k2s.
// ---------------------------------------------------------------------------
__global__ __launch_bounds__(256) void k2pre(
    const float* __restrict__ Sp, const float* __restrict__ Zp,
    float* __restrict__ Ssh, float* __restrict__ Zsh)
{
    const int q = blockIdx.x & 3;
    const int b = (blockIdx.x >> 2) & 1;
    const int s = blockIdx.x >> 3;
    const int t = threadIdx.x;
    const int i = q * 1024 + t * 4;
    float4 acc = {0.f, 0.f, 0.f, 0.f};
#pragma unroll
    for (int j = 0; j < 27; ++j) {
        const float4 v =
            *(const float4*)&Sp[(size_t)(b * 432 + s + 16 * j) * 4096 + i];
        acc.x += v.x; acc.y += v.y; acc.z += v.z; acc.w += v.w;
    }
    *(float4*)&Ssh[(size_t)(s * 2 + b) * 4096 + i] = acc;
    if (q == 0 && t < 128) {
        float z = 0.f;
#pragma unroll
        for (int j = 0; j < 27; ++j)
            z += Zp[(size_t)(b * 432 + s + 16 * j) * 128 + t];
        Zsh[(size_t)(s * 2 + b) * 128 + t] = z;
    }
}

// ---------------------------------------------------------------------------
// k2s: sum 16 shadows -> ctx = S/Z; P[c][hd] = sum_e wout[c][h*32+e]*ctx[h][d][e];
//      Weff[c][c2] = sum_hd P[c][hd]*wqkv[hd][c2] -> bf16
// ---------------------------------------------------------------------------
__global__ __launch_bounds__(1024) void k2s(
    const float* __restrict__ Ssh, const float* __restrict__ Zsh,
    const float* __restrict__ wout, const float* __restrict__ wqkv,
    unsigned short* __restrict__ WE)
{
    __shared__ float ctx[4][32][32];
    __shared__ float P[64][128];
    __shared__ float Zl[128];
    const int b = blockIdx.x;
    const int t = threadIdx.x;
    if (t < 128) {
        float z = 0.f;
#pragma unroll
        for (int s = 0; s < NSHADOW; ++s) z += Zsh[(size_t)(s * 2 + b) * 128 + t];
        Zl[t] = z;
    }
    __syncthreads();
    for (int i = t; i < 4096; i += 1024) {
        float sv = 0.f;
#pragma unroll
        for (int s = 0; s < NSHADOW; ++s) sv += Ssh[(size_t)(s * 2 + b) * 4096 + i];
        int h = i >> 10, d = (i >> 5) & 31;
        ctx[h][d][i & 31] = sv / Zl[h * 32 + d];
    }
    __syncthreads();
    for (int i = t; i < 8192; i += 1024) {
        int c = i >> 7, hd = i & 127, h = hd >> 5, d = hd & 31;
        const float* wo = wout + c * 128 + h * 32;
        float acc = 0.f;
#pragma unroll 8
        for (int e = 0; e < 32; ++e) acc += wo[e] * ctx[h][d][e];
        P[c][hd] = acc;
    }
    __syncthreads();
    for (int i = t; i < 4096; i += 1024) {
        int c = i >> 6, c2 = i & 63;
        float acc = 0.f;
#pragma unroll 8
        for (int hd = 0; hd < 128; ++hd) acc += P[c][hd] * wqkv[hd * 64 + c2];
        WE[b * 4096 + c * 64 + c2] = f2bf(acc);
    }
}

// ---------------------------------------------------------------------------
// k3f: out[b] = Weff[b]@x[b] + bias. 1728 blocks x 128-col strips. LDS-free;
// B-frags read as bf16 DIRECTLY from Xbf (k1's mirror) — half the bytes of
// k3e and no f2bf pass. Direct global stores. No LDS, no barriers.
// ---------------------------------------------------------------------------
__global__ __launch_bounds__(256) void k3f(
    const unsigned short* __restrict__ xbf, const unsigned short* __restrict__ WE,
    const float* __restrict__ bout, float* __restrict__ out)
{
    const int tid = threadIdx.x;
    const int wv = tid >> 6;
    const int l = tid & 63;
    const int l15 = l & 15, l4 = l >> 4;
    const int b = blockIdx.x / 864;
    const int n0 = (blockIdx.x % 864) * 128;

    s16x8 afr[4][2];
#pragma unroll
    for (int mt = 0; mt < 4; ++mt)
#pragma unroll
        for (int s = 0; s < 2; ++s)
            afr[mt][s] = *(const s16x8*)(WE + b * 4096 + (mt * 16 + l15) * 64 + s * 32 + l4 * 8);

    float bias[4][4];
#pragma unroll
    for (int mt = 0; mt < 4; ++mt)
#pragma unroll
        for (int r = 0; r < 4; ++r) bias[mt][r] = bout[mt * 16 + l4 * 4 + r];

    const unsigned short* xbfb = xbf + (size_t)b * 64 * NSP;
    float* ob = out + (size_t)b * 64 * NSP;

    const int nq = wv * 32;
    // lane's gather base: row l4*8, col n0+nq+l15
    const unsigned short* xq = xbfb + (size_t)(l4 * 8) * NSP + n0 + nq + l15;

    f32x4 acc[4][2] = {};
#pragma unroll
    for (int s = 0; s < 2; ++s) {
        // load 16 bf16: rows s*32+l4*8+j, cols {0,16}
        s16x8 b0, b1;  // B[k=s*32+l4*8+j][n=nt*16+l15]
#pragma unroll
        for (int j = 0; j < 8; ++j) {
            const unsigned short* p = xq + (size_t)(s * 32 + j) * NSP;
            b0[j] = (short)p[0];
            b1[j] = (short)p[16];
        }
#pragma unroll
        for (int mt = 0; mt < 4; ++mt) {
            acc[mt][0] = MFMA(afr[mt][s], b0, acc[mt][0]);
            acc[mt][1] = MFMA(afr[mt][s], b1, acc[mt][1]);
        }
    }

    // direct stores: for fixed (mt,nt,r) the wave writes 4 rows x 16
    // consecutive floats = 4 fully-utilized 64B segments.
#pragma unroll
    for (int mt = 0; mt < 4; ++mt)
#pragma unroll
        for (int nt = 0; nt < 2; ++nt)
#pragma unroll
            for (int r = 0; r < 4; ++r)
                ob[(size_t)(mt * 16 + l4 * 4 + r) * NSP + n0 + nq + nt * 16 + l15] =
                    acc[mt][nt][r] + bias[mt][r];
}

// ---------------------------------------------------------------------------
// k3e (fallback, small-ws path): identical to k3f but gathers fp32 x + f2bf.
// ---------------------------------------------------------------------------
__global__ __launch_bounds__(256) void k3e(
    const float* __restrict__ x, const unsigned short* __restrict__ WE,
    const float* __restrict__ bout, float* __restrict__ out)
{
    const int tid = threadIdx.x;
    const int wv = tid >> 6;
    const int l = tid & 63;
    const int l15 = l & 15, l4 = l >> 4;
    const int b = blockIdx.x / 864;
    const int n0 = (blockIdx.x % 864) * 128;

    s16x8 afr[4][2];
#pragma unroll
    for (int mt = 0; mt < 4; ++mt)
#pragma unroll
        for (int s = 0; s < 2; ++s)
            afr[mt][s] = *(const s16x8*)(WE + b * 4096 + (mt * 16 + l15) * 64 + s * 32 + l4 * 8);

    float bias[4][4];
#pragma unroll
    for (int mt = 0; mt < 4; ++mt)
#pragma unroll
        for (int r = 0; r < 4; ++r) bias[mt][r] = bout[mt * 16 + l4 * 4 + r];

    const float* xb = x + (size_t)b * 64 * NSP;
    float* ob = out + (size_t)b * 64 * NSP;

    const int nq = wv * 32;
    const float* xq = xb + (size_t)(l4 * 8) * NSP + n0 + nq + l15;

    f32x4 acc[4][2] = {};
#pragma unroll
    for (int s = 0; s < 2; ++s) {
        float t0[8], t1[8];
#pragma unroll
        for (int j = 0; j < 8; ++j) {
            const float* p = xq + (size_t)(s * 32 + j) * NSP;
            t0[j] = p[0];
            t1[j] = p[16];
        }
        s16x8 b0, b1;
#pragma unroll
        for (int j = 0; j < 8; ++j) {
            b0[j] = (short)f2bf(t0[j]);
            b1[j] = (short)f2bf(t1[j]);
        }
#pragma unroll
        for (int mt = 0; mt < 4; ++mt) {
            acc[mt][0] = MFMA(afr[mt][s], b0, acc[mt][0]);
            acc[mt][1] = MFMA(afr[mt][s], b1, acc[mt][1]);
        }
    }

#pragma unroll
    for (int mt = 0; mt < 4; ++mt)
#pragma unroll
        for (int nt = 0; nt < 2; ++nt)
#pragma unroll
            for (int r = 0; r < 4; ++r)
                ob[(size_t)(mt * 16 + l4 * 4 + r) * NSP + n0 + nq + nt * 16 + l15] =
                    acc[mt][nt][r] + bias[mt][r];
}

extern "C" void kernel_launch(void* const* d_in, const int* in_sizes, int n_in,
                              void* d_out, int out_size, void* d_ws, size_t ws_size,
                              hipStream_t stream) {
    // Inputs by size (order-proof): x=14155776, w_qkv=24576, w_out=8192, b_out=64.
    const float *x = nullptr, *wqkv = nullptr, *wout = nullptr, *bout = nullptr;
    for (int i = 0; i < n_in; ++i) {
        if (in_sizes[i] == 2 * 64 * NSP) x = (const float*)d_in[i];
        else if (in_sizes[i] == 384 * 64) wqkv = (const float*)d_in[i];
        else if (in_sizes[i] == 64 * 128) wout = (const float*)d_in[i];
        else if (in_sizes[i] == 64) bout = (const float*)d_in[i];
    }
    if (!x) x = (const float*)d_in[0];
    if (!wqkv) wqkv = (const float*)d_in[1];
    if (!wout) wout = (const float*)d_in[2];
    if (!bout) bout = (const float*)d_in[3];
    float* out = (float*)d_out;

    // big path layout:
    //   Sp fp32[864][4096]    @0              (14155776 B)
    //   Zp fp32[864][128]     @14155776       (442368 B)
    //   Ssh fp32[16][2][4096] @14598144       (524288 B)
    //   Zsh fp32[16][2][128]  @15122432       (16384 B)
    //   WE bf16[2][4096]      @15138816       (16384 B)
    //   Xbf bf16[2][64][NSP]  @15155200       (28311552 B)   end: 43466752
    // small path (fallback): Ssh @0, Zsh @524288, WE @540672 (atomics)
    const size_t NEED_BIG = 43466752;
    if (ws_size >= NEED_BIG) {
        float* Sp = (float*)d_ws;
        float* Zp = (float*)((char*)d_ws + 14155776);
        float* Ssh = (float*)((char*)d_ws + 14598144);
        float* Zsh = (float*)((char*)d_ws + 15122432);
        unsigned short* WE = (unsigned short*)((char*)d_ws + 15138816);
        unsigned short* Xbf = (unsigned short*)((char*)d_ws + 15155200);
        hipLaunchKernelGGL(k1y, dim3(864), dim3(256), 0, stream, x, wqkv, Sp, Zp, Xbf, 0);
        hipLaunchKernelGGL(k2pre, dim3(128), dim3(256), 0, stream, Sp, Zp, Ssh, Zsh);
        hipLaunchKernelGGL(k2s, dim3(2), dim3(1024), 0, stream, Ssh, Zsh, wout, wqkv, WE);
        hipLaunchKernelGGL(k3f, dim3(1728), dim3(256), 0, stream, Xbf, WE, bout, out);
    } else {
        float* Ssh = (float*)d_ws;
        float* Zsh = (float*)((char*)d_ws + 524288);
        unsigned short* WE = (unsigned short*)((char*)d_ws + 540672);
        hipMemsetAsync(d_ws, 0, 540672, stream);  // zero shadows
        hipLaunchKernelGGL(k1y, dim3(864), dim3(256), 0, stream, x, wqkv, Ssh, Zsh,
                           (unsigned short*)nullptr, 1);
        hipLaunchKernelGGL(k2s, dim3(2), dim3(1024), 0, stream, Ssh, Zsh, wout, wqkv, WE);
        hipLaunchKernelGGL(k3e, dim3(1728), dim3(256), 0, stream, x, WE, bout, out);
    }
}

// Round 11
// 176.781 us; speedup vs baseline: 1.4678x; 1.0455x over previous
//
#include <hip/hip_runtime.h>
#include <stdint.h>

// LinearAttention (literal listing, softmax over n):
//   ctx_h = softmax_n(K_h) @ V_h^T;  out = wout·(ctx^T ⊛ q) + b
//   collapsed: out[b] = Weff[b]@x[b]+b,  Weff = wout·blockdiag(ctx^T)·W_q
// ROUND 21:
//  * R10 post-mortem: Xbf mirror was traffic-neutral BY CONSTRUCTION
//    (56.6+28.3+28.3 == 56.6+56.6) and regressed 9.4us (churn + stores on
//    latency-bound k1). Reverted. Rule: write the bytes equation FIRST.
//  * k1z: 1152 blocks x 6 tiles, SINGLE-buffer XT, lb(256,4) kept.
//    De-confounded from R9: that spill came from lb(256,5)'s VGPR<=102 cap
//    (body needs ~104 at 64 reported); structure itself passed numerically.
//    LDS 37.9->29.2KB; grid 4.5 blk/CU (+33% concurrency vs 864's 3.375).
//    Partials 18.9MB (between 864's 14.6 and 1728's churn-prone 28.3).
//  * k2pre: 36 summands (1152 partials), 128 blocks. k2s unchanged.
//  * k3e: R7's proven LDS-free direct-gather kernel, fp32 x (no mirror).
//  * Fixed harness overhead ~82-97us/iter (ws poison fills).
// VGPR watch: k1z < 60 => spilled => next round reverts to R7 verbatim.

using f32x4 = __attribute__((ext_vector_type(4))) float;
using s16x8 = __attribute__((ext_vector_type(8))) short;

#define NSP 110592  // 48*48*48
#define NSHADOW 16
#define MFMA(a, b, c) __builtin_amdgcn_mfma_f32_16x16x32_bf16((a), (b), (c), 0, 0, 0)

static __device__ __forceinline__ unsigned short f2bf(float f) {
    return (unsigned short)((__float_as_uint(f) + 0x8000u) >> 16);  // round-half-up
}

// ---------------------------------------------------------------------------
// k1z: 1152 blocks (576/batch), 6 contiguous 32-n tiles, single-buffer XT
// (2 barriers/iter, cross-tile prefetch in regs — R8 loop structure, proven
// numerically correct in R9). Round-0 compute body, plain-store flush.
// mode 0: per-block partial stores to Sp/Zp. mode 1: 16-shadow atomics.
// ---------------------------------------------------------------------------
__global__ __launch_bounds__(256, 4) void k1z(
    const float* __restrict__ x, const float* __restrict__ wqkv,
    float* __restrict__ Sdst, float* __restrict__ Zdst, int mode)
{
    __shared__ unsigned short XT[64][68];         // single staged x tile (bf16)
    __shared__ unsigned short EKV[4][2][32][40];  // wave-private [K/V][row][col]
    const int tid = threadIdx.x;
    const int wv = tid >> 6;
    const int l = tid & 63;
    const int l15 = l & 15, l4 = l >> 4;
    const int blk = blockIdx.x;
    const int b = blk / 576;            // 576 blocks/batch
    const int tbase = (blk % 576) * 6;  // 6 contiguous tiles
    const int h = wv;

    // A-frags: rows of W_k (128+h*32+m) / W_v (256+h*32+m); A[m=l15][k=l4*8+j]
    s16x8 afr[2][2][2];  // [kv][mtile][kstep]
    for (int kv = 0; kv < 2; ++kv)
        for (int mt = 0; mt < 2; ++mt)
            for (int s = 0; s < 2; ++s) {
                int row = 128 + kv * 128 + h * 32 + mt * 16 + l15;
                const float* wp = wqkv + row * 64 + s * 32 + l4 * 8;
                s16x8 a;
#pragma unroll
                for (int j = 0; j < 8; ++j) a[j] = (short)f2bf(wp[j]);
                afr[kv][mt][s] = a;
            }

    f32x4 sacc[2][2] = {};
    float zrow[8] = {};

    unsigned short (*EK)[40] = EKV[wv][0];
    unsigned short (*EV)[40] = EKV[wv][1];
    const float* xb = x + (size_t)b * 64 * NSP;

    // staging addresses for this thread (2 float4 per tile)
    const int c0 = tid >> 3;                        // p=0 row
    const int ng0 = (tid & 7) ^ (c0 & 7);
    const int c1 = (tid + 256) >> 3;                // p=1 row
    const int ng1 = ((tid + 256) & 7) ^ (c1 & 7);

    float4 g0, g1;
    {   // preload tile 0
        const int n0 = tbase * 32;
        g0 = *(const float4*)(xb + (size_t)c0 * NSP + n0 + 4 * ng0);
        g1 = *(const float4*)(xb + (size_t)c1 * NSP + n0 + 4 * ng1);
    }

    for (int it = 0; it < 6; ++it) {
        if (it > 0) __syncthreads();  // all waves done READING XT from iter-1
        // write staged regs -> XT
        {
            ushort4 u0, u1;
            u0.x = f2bf(g0.x); u0.y = f2bf(g0.y); u0.z = f2bf(g0.z); u0.w = f2bf(g0.w);
            u1.x = f2bf(g1.x); u1.y = f2bf(g1.y); u1.z = f2bf(g1.z); u1.w = f2bf(g1.w);
            *(ushort4*)&XT[c0][4 * ng0] = u0;
            *(ushort4*)&XT[c1][4 * ng1] = u1;
        }
        // issue next tile's loads; they land during this iter's compute
        if (it < 5) {
            const int n0 = (tbase + it + 1) * 32;
            g0 = *(const float4*)(xb + (size_t)c0 * NSP + n0 + 4 * ng0);
            g1 = *(const float4*)(xb + (size_t)c1 * NSP + n0 + 4 * ng1);
        }
        __syncthreads();              // XT writes visible

        // GEMM1: [K_h;V_h] = W @ xtile (M=64,K=64,N=32)
        f32x4 ck[2][2] = {}, cv[2][2] = {};
#pragma unroll
        for (int s = 0; s < 2; ++s)
#pragma unroll
            for (int nt = 0; nt < 2; ++nt) {
                s16x8 bfr;  // B[k=c][n]: n=l15, c=l4*8+j (+32s)
#pragma unroll
                for (int j = 0; j < 8; ++j)
                    bfr[j] = (short)XT[s * 32 + l4 * 8 + j][nt * 16 + l15];
#pragma unroll
                for (int mt = 0; mt < 2; ++mt) {
                    ck[mt][nt] = MFMA(afr[0][mt][s], bfr, ck[mt][nt]);
                    cv[mt][nt] = MFMA(afr[1][mt][s], bfr, cv[mt][nt]);
                }
            }
        // exp -> Z(regs) + EK; V -> EV   (C: row=mt*16+l4*4+r, col=nt*16+l15)
#pragma unroll
        for (int mt = 0; mt < 2; ++mt)
#pragma unroll
            for (int nt = 0; nt < 2; ++nt) {
                int col = nt * 16 + l15;
#pragma unroll
                for (int r = 0; r < 4; ++r) {
                    int row = mt * 16 + l4 * 4 + r;
                    float ek = __expf(ck[mt][nt][r]);
                    zrow[mt * 4 + r] += ek;
                    EK[row][col] = f2bf(ek);
                    EV[row][col] = f2bf(cv[mt][nt][r]);
                }
            }
        // GEMM2: S_h += expK(32x32) @ V^T (wave-private, in-order DS pipe)
#pragma unroll
        for (int td = 0; td < 2; ++td) {
            s16x8 a2 = *(const s16x8*)&EK[td * 16 + l15][l4 * 8];
#pragma unroll
            for (int te = 0; te < 2; ++te) {
                s16x8 b2 = *(const s16x8*)&EV[te * 16 + l15][l4 * 8];
                sacc[td][te] = MFMA(a2, b2, sacc[td][te]);
            }
        }
    }

    // Z: butterfly over the 16 replicating l15 lanes
#pragma unroll
    for (int i = 0; i < 8; ++i) {
        float z = zrow[i];
        z += __shfl_xor(z, 1);
        z += __shfl_xor(z, 2);
        z += __shfl_xor(z, 4);
        z += __shfl_xor(z, 8);
        zrow[i] = z;
    }

    if (mode == 0) {
        // per-block partial: plain stores, fully written, no zeroing needed
        float* Zb = Zdst + (size_t)blk * 128;
        if (l15 == 0)
#pragma unroll
            for (int mt = 0; mt < 2; ++mt)
#pragma unroll
                for (int r = 0; r < 4; ++r)
                    Zb[h * 32 + mt * 16 + l4 * 4 + r] = zrow[mt * 4 + r];
        float* Sb = Sdst + (size_t)blk * 4096 + h * 1024;
#pragma unroll
        for (int td = 0; td < 2; ++td)
#pragma unroll
            for (int te = 0; te < 2; ++te)
#pragma unroll
                for (int r = 0; r < 4; ++r)
                    Sb[(td * 16 + l4 * 4 + r) * 32 + te * 16 + l15] =
                        sacc[td][te][r];
    } else {
        const int shadow = blk & (NSHADOW - 1);
        float* Zb = Zdst + (size_t)(shadow * 2 + b) * 128;
        if (l15 == 0)
#pragma unroll
            for (int mt = 0; mt < 2; ++mt)
#pragma unroll
                for (int r = 0; r < 4; ++r)
                    atomicAdd(&Zb[h * 32 + mt * 16 + l4 * 4 + r], zrow[mt * 4 + r]);
        float* Sb = Sdst + (size_t)(shadow * 2 + b) * 4096 + h * 1024;
#pragma unroll
        for (int td = 0; td < 2; ++td)
#pragma unroll
            for (int te = 0; te < 2; ++te)
#pragma unroll
                for (int r = 0; r < 4; ++r)
                    atomicAdd(&Sb[(td * 16 + l4 * 4 + r) * 32 + te * 16 + l15],
                              sacc[td][te][r]);
    }
}

// ---------------------------------------------------------------------------
// k2pre: 128 blocks (16 groups x 2 batches x 4 quarter-rows) x 256 threads:
// sum 36 per-block partials (w = s + 16j) -> 16-intermediate layout for k2s.
// ---------------------------------------------------------------------------
__global__ __launch_bounds__(256) void k2pre(
    const float* __restrict__ Sp, const float* __restrict__ Zp,
    float* __restrict__ Ssh, float* __restrict__ Zsh)
{
    const int q = blockIdx.x & 3;
    const int b = (blockIdx.x >> 2) & 1;
    const int s = blockIdx.x >> 3;
    const int t = threadIdx.x;
    const int i = q * 1024 + t * 4;
    float4 acc = {0.f, 0.f, 0.f, 0.f};
#pragma unroll 6
    for (int j = 0; j < 36; ++j) {
        const float4 v =
            *(const float4*)&Sp[(size_t)(b * 576 + s + 16 * j) * 4096 + i];
        acc.x += v.x; acc.y += v.y; acc.z += v.z; acc.w += v.w;
    }
    *(float4*)&Ssh[(size_t)(s * 2 + b) * 4096 + i] = acc;
    if (q == 0 && t < 128) {
        float z = 0.f;
#pragma unroll 6
        for (int j = 0; j < 36; ++j)
            z += Zp[(size_t)(b * 576 + s + 16 * j) * 128 + t];
        Zsh[(size_t)(s * 2 + b) * 128 + t] = z;
    }
}

// ---------------------------------------------------------------------------
// k2s: sum 16 shadows -> ctx = S/Z; P[c][hd] = sum_e wout[c][h*32+e]*ctx[h][d][e];
//      Weff[c][c2] = sum_hd P[c][hd]*wqkv[hd][c2] -> bf16
// ---------------------------------------------------------------------------
__global__ __launch_bounds__(1024) void k2s(
    const float* __restrict__ Ssh, const float* __restrict__ Zsh,
    const float* __restrict__ wout, const float* __restrict__ wqkv,
    unsigned short* __restrict__ WE)
{
    __shared__ float ctx[4][32][32];
    __shared__ float P[64][128];
    __shared__ float Zl[128];
    const int b = blockIdx.x;
    const int t = threadIdx.x;
    if (t < 128) {
        float z = 0.f;
#pragma unroll
        for (int s = 0; s < NSHADOW; ++s) z += Zsh[(size_t)(s * 2 + b) * 128 + t];
        Zl[t] = z;
    }
    __syncthreads();
    for (int i = t; i < 4096; i += 1024) {
        float sv = 0.f;
#pragma unroll
        for (int s = 0; s < NSHADOW; ++s) sv += Ssh[(size_t)(s * 2 + b) * 4096 + i];
        int h = i >> 10, d = (i >> 5) & 31;
        ctx[h][d][i & 31] = sv / Zl[h * 32 + d];
    }
    __syncthreads();
    for (int i = t; i < 8192; i += 1024) {
        int c = i >> 7, hd = i & 127, h = hd >> 5, d = hd & 31;
        const float* wo = wout + c * 128 + h * 32;
        float acc = 0.f;
#pragma unroll 8
        for (int e = 0; e < 32; ++e) acc += wo[e] * ctx[h][d][e];
        P[c][hd] = acc;
    }
    __syncthreads();
    for (int i = t; i < 4096; i += 1024) {
        int c = i >> 6, c2 = i & 63;
        float acc = 0.f;
#pragma unroll 8
        for (int hd = 0; hd < 128; ++hd) acc += P[c][hd] * wqkv[hd * 64 + c2];
        WE[b * 4096 + c * 64 + c2] = f2bf(acc);
    }
}

// ---------------------------------------------------------------------------
// k3e: out[b] = Weff[b]@x[b] + bias. 1728 blocks x 128-col strips. LDS-FREE:
// each wave owns a disjoint 32-col slab (nq=wv*32); B-frags gathered straight
// from global (per load: 4 rows x 16 consecutive floats = 4x64B segments,
// x read exactly once per block), f2bf in regs, MFMA, direct global stores.
// No LDS, no barriers. (R7, proven.)
// ---------------------------------------------------------------------------
__global__ __launch_bounds__(256) void k3e(
    const float* __restrict__ x, const unsigned short* __restrict__ WE,
    const float* __restrict__ bout, float* __restrict__ out)
{
    const int tid = threadIdx.x;
    const int wv = tid >> 6;
    const int l = tid & 63;
    const int l15 = l & 15, l4 = l >> 4;
    const int b = blockIdx.x / 864;
    const int n0 = (blockIdx.x % 864) * 128;

    s16x8 afr[4][2];
#pragma unroll
    for (int mt = 0; mt < 4; ++mt)
#pragma unroll
        for (int s = 0; s < 2; ++s)
            afr[mt][s] = *(const s16x8*)(WE + b * 4096 + (mt * 16 + l15) * 64 + s * 32 + l4 * 8);

    float bias[4][4];
#pragma unroll
    for (int mt = 0; mt < 4; ++mt)
#pragma unroll
        for (int r = 0; r < 4; ++r) bias[mt][r] = bout[mt * 16 + l4 * 4 + r];

    const float* xb = x + (size_t)b * 64 * NSP;
    float* ob = out + (size_t)b * 64 * NSP;

    const int nq = wv * 32;
    // lane's gather base: row l4*8, col n0+nq+l15
    const float* xq = xb + (size_t)(l4 * 8) * NSP + n0 + nq + l15;

    f32x4 acc[4][2] = {};
#pragma unroll
    for (int s = 0; s < 2; ++s) {
        // load 16 floats: rows s*32+l4*8+j, cols {0,16}
        float t0[8], t1[8];
#pragma unroll
        for (int j = 0; j < 8; ++j) {
            const float* p = xq + (size_t)(s * 32 + j) * NSP;
            t0[j] = p[0];
            t1[j] = p[16];
        }
        s16x8 b0, b1;  // B[k=s*32+l4*8+j][n=nt*16+l15]
#pragma unroll
        for (int j = 0; j < 8; ++j) {
            b0[j] = (short)f2bf(t0[j]);
            b1[j] = (short)f2bf(t1[j]);
        }
#pragma unroll
        for (int mt = 0; mt < 4; ++mt) {
            acc[mt][0] = MFMA(afr[mt][s], b0, acc[mt][0]);
            acc[mt][1] = MFMA(afr[mt][s], b1, acc[mt][1]);
        }
    }

    // direct stores: for fixed (mt,nt,r) the wave writes 4 rows x 16
    // consecutive floats = 4 fully-utilized 64B segments.
#pragma unroll
    for (int mt = 0; mt < 4; ++mt)
#pragma unroll
        for (int nt = 0; nt < 2; ++nt)
#pragma unroll
            for (int r = 0; r < 4; ++r)
                ob[(size_t)(mt * 16 + l4 * 4 + r) * NSP + n0 + nq + nt * 16 + l15] =
                    acc[mt][nt][r] + bias[mt][r];
}

extern "C" void kernel_launch(void* const* d_in, const int* in_sizes, int n_in,
                              void* d_out, int out_size, void* d_ws, size_t ws_size,
                              hipStream_t stream) {
    // Inputs by size (order-proof): x=14155776, w_qkv=24576, w_out=8192, b_out=64.
    const float *x = nullptr, *wqkv = nullptr, *wout = nullptr, *bout = nullptr;
    for (int i = 0; i < n_in; ++i) {
        if (in_sizes[i] == 2 * 64 * NSP) x = (const float*)d_in[i];
        else if (in_sizes[i] == 384 * 64) wqkv = (const float*)d_in[i];
        else if (in_sizes[i] == 64 * 128) wout = (const float*)d_in[i];
        else if (in_sizes[i] == 64) bout = (const float*)d_in[i];
    }
    if (!x) x = (const float*)d_in[0];
    if (!wqkv) wqkv = (const float*)d_in[1];
    if (!wout) wout = (const float*)d_in[2];
    if (!bout) bout = (const float*)d_in[3];
    float* out = (float*)d_out;

    // big path layout:
    //   Sp fp32[1152][4096]   @0              (18874368 B)
    //   Zp fp32[1152][128]    @18874368       (589824 B)
    //   Ssh fp32[16][2][4096] @19464192       (524288 B)
    //   Zsh fp32[16][2][128]  @19988480       (16384 B)
    //   WE bf16[2][4096]      @20004864       (16384 B)   end: 20021248
    // small path (fallback): Ssh @0, Zsh @524288, WE @540672 (atomics)
    const size_t NEED_BIG = 20021248;
    if (ws_size >= NEED_BIG) {
        float* Sp = (float*)d_ws;
        float* Zp = (float*)((char*)d_ws + 18874368);
        float* Ssh = (float*)((char*)d_ws + 19464192);
        float* Zsh = (float*)((char*)d_ws + 19988480);
        unsigned short* WE = (unsigned short*)((char*)d_ws + 20004864);
        hipLaunchKernelGGL(k1z, dim3(1152), dim3(256), 0, stream, x, wqkv, Sp, Zp, 0);
        hipLaunchKernelGGL(k2pre, dim3(128), dim3(256), 0, stream, Sp, Zp, Ssh, Zsh);
        hipLaunchKernelGGL(k2s, dim3(2), dim3(1024), 0, stream, Ssh, Zsh, wout, wqkv, WE);
        hipLaunchKernelGGL(k3e, dim3(1728), dim3(256), 0, stream, x, WE, bout, out);
    } else {
        float* Ssh = (float*)d_ws;
        float* Zsh = (float*)((char*)d_ws + 524288);
        unsigned short* WE = (unsigned short*)((char*)d_ws + 540672);
        hipMemsetAsync(d_ws, 0, 540672, stream);  // zero shadows
        hipLaunchKernelGGL(k1z, dim3(1152), dim3(256), 0, stream, x, wqkv, Ssh, Zsh, 1);
        hipLaunchKernelGGL(k2s, dim3(2), dim3(1024), 0, stream, Ssh, Zsh, wout, wqkv, WE);
        hipLaunchKernelGGL(k3e, dim3(1728), dim3(256), 0, stream, x, WE, bout, out);
    }
}

// Round 12
// 154.032 us; speedup vs baseline: 1.6846x; 1.1477x over previous
//
#include <hip/hip_runtime.h>
#include <stdint.h>

// LinearAttention (literal listing, softmax over n):
//   ctx_h = softmax_n(K_h) @ V_h^T;  out = wout·(ctx^T ⊛ q) + b
//   collapsed: out[b] = Weff[b]@x[b]+b,  Weff = wout·blockdiag(ctx^T)·W_q
// ROUND 22:
//  * R11 FOUND THE HIDDEN 42us: k2s ran on 2 blocks (0.28% occupancy,
//    latency-serialized) and has cost ~42us ALL SESSION, hiding just under
//    the 41-42us fill threshold in top-5. k1z was neutral (kept).
//  * ONE change: split k2s -> k2a (8 blocks: shadow-sum + ctx=S/Z, 32KB to
//    ws) + k2b (128 blocks: P row + WE row per block). Same summation
//    orders -> bit-identical numerics. Predict k2a+k2b ~5us vs k2s 42us.
//  * k1z/k2pre/k3e unchanged from R11. Fallback path keeps original k2s.
//  * Fixed harness overhead: ONE ~42us poison fill/iter (recalibrated).

using f32x4 = __attribute__((ext_vector_type(4))) float;
using s16x8 = __attribute__((ext_vector_type(8))) short;

#define NSP 110592  // 48*48*48
#define NSHADOW 16
#define MFMA(a, b, c) __builtin_amdgcn_mfma_f32_16x16x32_bf16((a), (b), (c), 0, 0, 0)

static __device__ __forceinline__ unsigned short f2bf(float f) {
    return (unsigned short)((__float_as_uint(f) + 0x8000u) >> 16);  // round-half-up
}

// ---------------------------------------------------------------------------
// k1z: 1152 blocks (576/batch), 6 contiguous 32-n tiles, single-buffer XT
// (2 barriers/iter, cross-tile prefetch in regs). Round-0 compute body.
// mode 0: per-block partial stores to Sp/Zp. mode 1: 16-shadow atomics.
// ---------------------------------------------------------------------------
__global__ __launch_bounds__(256, 4) void k1z(
    const float* __restrict__ x, const float* __restrict__ wqkv,
    float* __restrict__ Sdst, float* __restrict__ Zdst, int mode)
{
    __shared__ unsigned short XT[64][68];         // single staged x tile (bf16)
    __shared__ unsigned short EKV[4][2][32][40];  // wave-private [K/V][row][col]
    const int tid = threadIdx.x;
    const int wv = tid >> 6;
    const int l = tid & 63;
    const int l15 = l & 15, l4 = l >> 4;
    const int blk = blockIdx.x;
    const int b = blk / 576;            // 576 blocks/batch
    const int tbase = (blk % 576) * 6;  // 6 contiguous tiles
    const int h = wv;

    // A-frags: rows of W_k (128+h*32+m) / W_v (256+h*32+m); A[m=l15][k=l4*8+j]
    s16x8 afr[2][2][2];  // [kv][mtile][kstep]
    for (int kv = 0; kv < 2; ++kv)
        for (int mt = 0; mt < 2; ++mt)
            for (int s = 0; s < 2; ++s) {
                int row = 128 + kv * 128 + h * 32 + mt * 16 + l15;
                const float* wp = wqkv + row * 64 + s * 32 + l4 * 8;
                s16x8 a;
#pragma unroll
                for (int j = 0; j < 8; ++j) a[j] = (short)f2bf(wp[j]);
                afr[kv][mt][s] = a;
            }

    f32x4 sacc[2][2] = {};
    float zrow[8] = {};

    unsigned short (*EK)[40] = EKV[wv][0];
    unsigned short (*EV)[40] = EKV[wv][1];
    const float* xb = x + (size_t)b * 64 * NSP;

    // staging addresses for this thread (2 float4 per tile)
    const int c0 = tid >> 3;                        // p=0 row
    const int ng0 = (tid & 7) ^ (c0 & 7);
    const int c1 = (tid + 256) >> 3;                // p=1 row
    const int ng1 = ((tid + 256) & 7) ^ (c1 & 7);

    float4 g0, g1;
    {   // preload tile 0
        const int n0 = tbase * 32;
        g0 = *(const float4*)(xb + (size_t)c0 * NSP + n0 + 4 * ng0);
        g1 = *(const float4*)(xb + (size_t)c1 * NSP + n0 + 4 * ng1);
    }

    for (int it = 0; it < 6; ++it) {
        if (it > 0) __syncthreads();  // all waves done READING XT from iter-1
        // write staged regs -> XT
        {
            ushort4 u0, u1;
            u0.x = f2bf(g0.x); u0.y = f2bf(g0.y); u0.z = f2bf(g0.z); u0.w = f2bf(g0.w);
            u1.x = f2bf(g1.x); u1.y = f2bf(g1.y); u1.z = f2bf(g1.z); u1.w = f2bf(g1.w);
            *(ushort4*)&XT[c0][4 * ng0] = u0;
            *(ushort4*)&XT[c1][4 * ng1] = u1;
        }
        // issue next tile's loads; they land during this iter's compute
        if (it < 5) {
            const int n0 = (tbase + it + 1) * 32;
            g0 = *(const float4*)(xb + (size_t)c0 * NSP + n0 + 4 * ng0);
            g1 = *(const float4*)(xb + (size_t)c1 * NSP + n0 + 4 * ng1);
        }
        __syncthreads();              // XT writes visible

        // GEMM1: [K_h;V_h] = W @ xtile (M=64,K=64,N=32)
        f32x4 ck[2][2] = {}, cv[2][2] = {};
#pragma unroll
        for (int s = 0; s < 2; ++s)
#pragma unroll
            for (int nt = 0; nt < 2; ++nt) {
                s16x8 bfr;  // B[k=c][n]: n=l15, c=l4*8+j (+32s)
#pragma unroll
                for (int j = 0; j < 8; ++j)
                    bfr[j] = (short)XT[s * 32 + l4 * 8 + j][nt * 16 + l15];
#pragma unroll
                for (int mt = 0; mt < 2; ++mt) {
                    ck[mt][nt] = MFMA(afr[0][mt][s], bfr, ck[mt][nt]);
                    cv[mt][nt] = MFMA(afr[1][mt][s], bfr, cv[mt][nt]);
                }
            }
        // exp -> Z(regs) + EK; V -> EV   (C: row=mt*16+l4*4+r, col=nt*16+l15)
#pragma unroll
        for (int mt = 0; mt < 2; ++mt)
#pragma unroll
            for (int nt = 0; nt < 2; ++nt) {
                int col = nt * 16 + l15;
#pragma unroll
                for (int r = 0; r < 4; ++r) {
                    int row = mt * 16 + l4 * 4 + r;
                    float ek = __expf(ck[mt][nt][r]);
                    zrow[mt * 4 + r] += ek;
                    EK[row][col] = f2bf(ek);
                    EV[row][col] = f2bf(cv[mt][nt][r]);
                }
            }
        // GEMM2: S_h += expK(32x32) @ V^T (wave-private, in-order DS pipe)
#pragma unroll
        for (int td = 0; td < 2; ++td) {
            s16x8 a2 = *(const s16x8*)&EK[td * 16 + l15][l4 * 8];
#pragma unroll
            for (int te = 0; te < 2; ++te) {
                s16x8 b2 = *(const s16x8*)&EV[te * 16 + l15][l4 * 8];
                sacc[td][te] = MFMA(a2, b2, sacc[td][te]);
            }
        }
    }

    // Z: butterfly over the 16 replicating l15 lanes
#pragma unroll
    for (int i = 0; i < 8; ++i) {
        float z = zrow[i];
        z += __shfl_xor(z, 1);
        z += __shfl_xor(z, 2);
        z += __shfl_xor(z, 4);
        z += __shfl_xor(z, 8);
        zrow[i] = z;
    }

    if (mode == 0) {
        // per-block partial: plain stores, fully written, no zeroing needed
        float* Zb = Zdst + (size_t)blk * 128;
        if (l15 == 0)
#pragma unroll
            for (int mt = 0; mt < 2; ++mt)
#pragma unroll
                for (int r = 0; r < 4; ++r)
                    Zb[h * 32 + mt * 16 + l4 * 4 + r] = zrow[mt * 4 + r];
        float* Sb = Sdst + (size_t)blk * 4096 + h * 1024;
#pragma unroll
        for (int td = 0; td < 2; ++td)
#pragma unroll
            for (int te = 0; te < 2; ++te)
#pragma unroll
                for (int r = 0; r < 4; ++r)
                    Sb[(td * 16 + l4 * 4 + r) * 32 + te * 16 + l15] =
                        sacc[td][te][r];
    } else {
        const int shadow = blk & (NSHADOW - 1);
        float* Zb = Zdst + (size_t)(shadow * 2 + b) * 128;
        if (l15 == 0)
#pragma unroll
            for (int mt = 0; mt < 2; ++mt)
#pragma unroll
                for (int r = 0; r < 4; ++r)
                    atomicAdd(&Zb[h * 32 + mt * 16 + l4 * 4 + r], zrow[mt * 4 + r]);
        float* Sb = Sdst + (size_t)(shadow * 2 + b) * 4096 + h * 1024;
#pragma unroll
        for (int td = 0; td < 2; ++td)
#pragma unroll
            for (int te = 0; te < 2; ++te)
#pragma unroll
                for (int r = 0; r < 4; ++r)
                    atomicAdd(&Sb[(td * 16 + l4 * 4 + r) * 32 + te * 16 + l15],
                              sacc[td][te][r]);
    }
}

// ---------------------------------------------------------------------------
// k2pre: 128 blocks (16 groups x 2 batches x 4 quarter-rows) x 256 threads:
// sum 36 per-block partials (w = s + 16j) -> 16-intermediate layout.
// ---------------------------------------------------------------------------
__global__ __launch_bounds__(256) void k2pre(
    const float* __restrict__ Sp, const float* __restrict__ Zp,
    float* __restrict__ Ssh, float* __restrict__ Zsh)
{
    const int q = blockIdx.x & 3;
    const int b = (blockIdx.x >> 2) & 1;
    const int s = blockIdx.x >> 3;
    const int t = threadIdx.x;
    const int i = q * 1024 + t * 4;
    float4 acc = {0.f, 0.f, 0.f, 0.f};
#pragma unroll 6
    for (int j = 0; j < 36; ++j) {
        const float4 v =
            *(const float4*)&Sp[(size_t)(b * 576 + s + 16 * j) * 4096 + i];
        acc.x += v.x; acc.y += v.y; acc.z += v.z; acc.w += v.w;
    }
    *(float4*)&Ssh[(size_t)(s * 2 + b) * 4096 + i] = acc;
    if (q == 0 && t < 128) {
        float z = 0.f;
#pragma unroll 6
        for (int j = 0; j < 36; ++j)
            z += Zp[(size_t)(b * 576 + s + 16 * j) * 128 + t];
        Zsh[(size_t)(s * 2 + b) * 128 + t] = z;
    }
}

// ---------------------------------------------------------------------------
// k2a: 8 blocks (2 batches x 4 heads) x 256 threads: sum 16 shadows ->
// ctx[b][h][d][e] = S/Z, written to ws. Same summation order as old k2s.
// ---------------------------------------------------------------------------
__global__ __launch_bounds__(256) void k2a(
    const float* __restrict__ Ssh, const float* __restrict__ Zsh,
    float* __restrict__ ctxg)
{
    __shared__ float Zl[32];
    const int b = blockIdx.x & 1;
    const int h = blockIdx.x >> 1;
    const int t = threadIdx.x;
    if (t < 32) {
        float z = 0.f;
#pragma unroll
        for (int s = 0; s < NSHADOW; ++s)
            z += Zsh[(size_t)(s * 2 + b) * 128 + h * 32 + t];
        Zl[t] = z;
    }
    __syncthreads();
    const int li = t * 4;           // 4 consecutive e, same d
    const int d = li >> 5;
    float4 sv = {0.f, 0.f, 0.f, 0.f};
#pragma unroll
    for (int s = 0; s < NSHADOW; ++s) {
        const float4 v = *(const float4*)&Ssh[(size_t)(s * 2 + b) * 4096 + h * 1024 + li];
        sv.x += v.x; sv.y += v.y; sv.z += v.z; sv.w += v.w;
    }
    const float zi = Zl[d];
    sv.x /= zi; sv.y /= zi; sv.z /= zi; sv.w /= zi;
    *(float4*)&ctxg[(size_t)(b * 4 + h) * 1024 + li] = sv;
}

// ---------------------------------------------------------------------------
// k2b: 128 blocks (2 batches x 64 c) x 128 threads: P[hd=t] = wout[c] . ctx,
// LDS, then t<64: WE[c][c2=t] = P . wqkv[:,c2]. Same loop orders as old k2s.
// ---------------------------------------------------------------------------
__global__ __launch_bounds__(128) void k2b(
    const float* __restrict__ ctxg, const float* __restrict__ wout,
    const float* __restrict__ wqkv, unsigned short* __restrict__ WE)
{
    __shared__ float P[128];
    const int b = blockIdx.x >> 6;
    const int c = blockIdx.x & 63;
    const int t = threadIdx.x;
    {   // P[c][hd] for hd = t
        const int h = t >> 5, d = t & 31;
        const float* wo = wout + c * 128 + h * 32;
        const float* cx = ctxg + (size_t)(b * 4 + h) * 1024 + d * 32;
        float acc = 0.f;
#pragma unroll 8
        for (int e = 0; e < 32; ++e) acc += wo[e] * cx[e];
        P[t] = acc;
    }
    __syncthreads();
    if (t < 64) {
        float acc = 0.f;
#pragma unroll 8
        for (int hd = 0; hd < 128; ++hd) acc += P[hd] * wqkv[hd * 64 + t];
        WE[b * 4096 + c * 64 + t] = f2bf(acc);
    }
}

// ---------------------------------------------------------------------------
// k2s (fallback path only): original 2-block kernel.
// ---------------------------------------------------------------------------
__global__ __launch_bounds__(1024) void k2s(
    const float* __restrict__ Ssh, const float* __restrict__ Zsh,
    const float* __restrict__ wout, const float* __restrict__ wqkv,
    unsigned short* __restrict__ WE)
{
    __shared__ float ctx[4][32][32];
    __shared__ float P[64][128];
    __shared__ float Zl[128];
    const int b = blockIdx.x;
    const int t = threadIdx.x;
    if (t < 128) {
        float z = 0.f;
#pragma unroll
        for (int s = 0; s < NSHADOW; ++s) z += Zsh[(size_t)(s * 2 + b) * 128 + t];
        Zl[t] = z;
    }
    __syncthreads();
    for (int i = t; i < 4096; i += 1024) {
        float sv = 0.f;
#pragma unroll
        for (int s = 0; s < NSHADOW; ++s) sv += Ssh[(size_t)(s * 2 + b) * 4096 + i];
        int h = i >> 10, d = (i >> 5) & 31;
        ctx[h][d][i & 31] = sv / Zl[h * 32 + d];
    }
    __syncthreads();
    for (int i = t; i < 8192; i += 1024) {
        int c = i >> 7, hd = i & 127, h = hd >> 5, d = hd & 31;
        const float* wo = wout + c * 128 + h * 32;
        float acc = 0.f;
#pragma unroll 8
        for (int e = 0; e < 32; ++e) acc += wo[e] * ctx[h][d][e];
        P[c][hd] = acc;
    }
    __syncthreads();
    for (int i = t; i < 4096; i += 1024) {
        int c = i >> 6, c2 = i & 63;
        float acc = 0.f;
#pragma unroll 8
        for (int hd = 0; hd < 128; ++hd) acc += P[c][hd] * wqkv[hd * 64 + c2];
        WE[b * 4096 + c * 64 + c2] = f2bf(acc);
    }
}

// ---------------------------------------------------------------------------
// k3e: out[b] = Weff[b]@x[b] + bias. 1728 blocks x 128-col strips. LDS-FREE:
// per-wave disjoint 32-col slab; B-frags straight from global (4x64B
// segments/instr, x read once/block), f2bf in regs, MFMA, direct stores.
// ---------------------------------------------------------------------------
__global__ __launch_bounds__(256) void k3e(
    const float* __restrict__ x, const unsigned short* __restrict__ WE,
    const float* __restrict__ bout, float* __restrict__ out)
{
    const int tid = threadIdx.x;
    const int wv = tid >> 6;
    const int l = tid & 63;
    const int l15 = l & 15, l4 = l >> 4;
    const int b = blockIdx.x / 864;
    const int n0 = (blockIdx.x % 864) * 128;

    s16x8 afr[4][2];
#pragma unroll
    for (int mt = 0; mt < 4; ++mt)
#pragma unroll
        for (int s = 0; s < 2; ++s)
            afr[mt][s] = *(const s16x8*)(WE + b * 4096 + (mt * 16 + l15) * 64 + s * 32 + l4 * 8);

    float bias[4][4];
#pragma unroll
    for (int mt = 0; mt < 4; ++mt)
#pragma unroll
        for (int r = 0; r < 4; ++r) bias[mt][r] = bout[mt * 16 + l4 * 4 + r];

    const float* xb = x + (size_t)b * 64 * NSP;
    float* ob = out + (size_t)b * 64 * NSP;

    const int nq = wv * 32;
    const float* xq = xb + (size_t)(l4 * 8) * NSP + n0 + nq + l15;

    f32x4 acc[4][2] = {};
#pragma unroll
    for (int s = 0; s < 2; ++s) {
        float t0[8], t1[8];
#pragma unroll
        for (int j = 0; j < 8; ++j) {
            const float* p = xq + (size_t)(s * 32 + j) * NSP;
            t0[j] = p[0];
            t1[j] = p[16];
        }
        s16x8 b0, b1;
#pragma unroll
        for (int j = 0; j < 8; ++j) {
            b0[j] = (short)f2bf(t0[j]);
            b1[j] = (short)f2bf(t1[j]);
        }
#pragma unroll
        for (int mt = 0; mt < 4; ++mt) {
            acc[mt][0] = MFMA(afr[mt][s], b0, acc[mt][0]);
            acc[mt][1] = MFMA(afr[mt][s], b1, acc[mt][1]);
        }
    }

#pragma unroll
    for (int mt = 0; mt < 4; ++mt)
#pragma unroll
        for (int nt = 0; nt < 2; ++nt)
#pragma unroll
            for (int r = 0; r < 4; ++r)
                ob[(size_t)(mt * 16 + l4 * 4 + r) * NSP + n0 + nq + nt * 16 + l15] =
                    acc[mt][nt][r] + bias[mt][r];
}

extern "C" void kernel_launch(void* const* d_in, const int* in_sizes, int n_in,
                              void* d_out, int out_size, void* d_ws, size_t ws_size,
                              hipStream_t stream) {
    // Inputs by size (order-proof): x=14155776, w_qkv=24576, w_out=8192, b_out=64.
    const float *x = nullptr, *wqkv = nullptr, *wout = nullptr, *bout = nullptr;
    for (int i = 0; i < n_in; ++i) {
        if (in_sizes[i] == 2 * 64 * NSP) x = (const float*)d_in[i];
        else if (in_sizes[i] == 384 * 64) wqkv = (const float*)d_in[i];
        else if (in_sizes[i] == 64 * 128) wout = (const float*)d_in[i];
        else if (in_sizes[i] == 64) bout = (const float*)d_in[i];
    }
    if (!x) x = (const float*)d_in[0];
    if (!wqkv) wqkv = (const float*)d_in[1];
    if (!wout) wout = (const float*)d_in[2];
    if (!bout) bout = (const float*)d_in[3];
    float* out = (float*)d_out;

    // big path layout:
    //   Sp fp32[1152][4096]   @0              (18874368 B)
    //   Zp fp32[1152][128]    @18874368       (589824 B)
    //   Ssh fp32[16][2][4096] @19464192       (524288 B)
    //   Zsh fp32[16][2][128]  @19988480       (16384 B)
    //   WE bf16[2][4096]      @20004864       (16384 B)
    //   ctx fp32[2][4][1024]  @20021248       (32768 B)   end: 20054016
    // small path (fallback): Ssh @0, Zsh @524288, WE @540672 (atomics)
    const size_t NEED_BIG = 20054016;
    if (ws_size >= NEED_BIG) {
        float* Sp = (float*)d_ws;
        float* Zp = (float*)((char*)d_ws + 18874368);
        float* Ssh = (float*)((char*)d_ws + 19464192);
        float* Zsh = (float*)((char*)d_ws + 19988480);
        unsigned short* WE = (unsigned short*)((char*)d_ws + 20004864);
        float* ctxg = (float*)((char*)d_ws + 20021248);
        hipLaunchKernelGGL(k1z, dim3(1152), dim3(256), 0, stream, x, wqkv, Sp, Zp, 0);
        hipLaunchKernelGGL(k2pre, dim3(128), dim3(256), 0, stream, Sp, Zp, Ssh, Zsh);
        hipLaunchKernelGGL(k2a, dim3(8), dim3(256), 0, stream, Ssh, Zsh, ctxg);
        hipLaunchKernelGGL(k2b, dim3(128), dim3(128), 0, stream, ctxg, wout, wqkv, WE);
        hipLaunchKernelGGL(k3e, dim3(1728), dim3(256), 0, stream, x, WE, bout, out);
    } else {
        float* Ssh = (float*)d_ws;
        float* Zsh = (float*)((char*)d_ws + 524288);
        unsigned short* WE = (unsigned short*)((char*)d_ws + 540672);
        hipMemsetAsync(d_ws, 0, 540672, stream);  // zero shadows
        hipLaunchKernelGGL(k1z, dim3(1152), dim3(256), 0, stream, x, wqkv, Ssh, Zsh, 1);
        hipLaunchKernelGGL(k2s, dim3(2), dim3(1024), 0, stream, Ssh, Zsh, wout, wqkv, WE);
        hipLaunchKernelGGL(k3e, dim3(1728), dim3(256), 0, stream, x, WE, bout, out);
    }
}

// Round 13
// 151.444 us; speedup vs baseline: 1.7134x; 1.0171x over previous
//
#include <hip/hip_runtime.h>
#include <stdint.h>

// LinearAttention (literal listing, softmax over n):
//   ctx_h = softmax_n(K_h) @ V_h^T;  out = wout·(ctx^T ⊛ q) + b
//   collapsed: out[b] = Weff[b]@x[b]+b,  Weff = wout·blockdiag(ctx^T)·W_q
// ROUND 23:
//  * R12: k2s split WIN (176.8->154.0). Top-5 = fills only again.
//  * k1z gather = 4-way bank conflict (derived: row stride 136B = 34 banks;
//    rows +16 alias the same 8 banks; SQ_LDS_BANK_CONFLICT 663552 == 24
//    extra cy/wave-tile == exactly the 32-read gather). Pad can't fix it
//    (ushort4 staging needs stride%8B==0; conflict-free needs %16==4).
//    FIX: XOR swizzle XT[c][col ^ (c&16)], gather col ^ (row&16) — the
//    (row&16) term is (l4>=2)*16, wave-uniform per lane; staging writes
//    stay 8B-aligned (col^16 == byte^32). Bit-identical data.
//    Predict: conflicts 663K -> <150K (model falsified if not), k1 ~39->36.
//  * k2pre: 512 blocks x 64 thr (1 wave each, 1/16-row slices) — 4x blocks
//    for the 18.9MB latency-bound reduce. Predict ~10 -> ~5.
//  * k2a/k2b (R12 win), k3e, fallback path unchanged.

using f32x4 = __attribute__((ext_vector_type(4))) float;
using s16x8 = __attribute__((ext_vector_type(8))) short;

#define NSP 110592  // 48*48*48
#define NSHADOW 16
#define MFMA(a, b, c) __builtin_amdgcn_mfma_f32_16x16x32_bf16((a), (b), (c), 0, 0, 0)

static __device__ __forceinline__ unsigned short f2bf(float f) {
    return (unsigned short)((__float_as_uint(f) + 0x8000u) >> 16);  // round-half-up
}

// ---------------------------------------------------------------------------
// k1z: 1152 blocks (576/batch), 6 contiguous 32-n tiles, single-buffer XT
// (2 barriers/iter, cross-tile prefetch in regs). XOR-swizzled XT layout:
// XT[c][col ^ (c&16)] — kills the 4-way gather bank conflict.
// mode 0: per-block partial stores to Sp/Zp. mode 1: 16-shadow atomics.
// ---------------------------------------------------------------------------
__global__ __launch_bounds__(256, 4) void k1z(
    const float* __restrict__ x, const float* __restrict__ wqkv,
    float* __restrict__ Sdst, float* __restrict__ Zdst, int mode)
{
    __shared__ unsigned short XT[64][68];         // single staged x tile (bf16)
    __shared__ unsigned short EKV[4][2][32][40];  // wave-private [K/V][row][col]
    const int tid = threadIdx.x;
    const int wv = tid >> 6;
    const int l = tid & 63;
    const int l15 = l & 15, l4 = l >> 4;
    const int blk = blockIdx.x;
    const int b = blk / 576;            // 576 blocks/batch
    const int tbase = (blk % 576) * 6;  // 6 contiguous tiles
    const int h = wv;

    // A-frags: rows of W_k (128+h*32+m) / W_v (256+h*32+m); A[m=l15][k=l4*8+j]
    s16x8 afr[2][2][2];  // [kv][mtile][kstep]
    for (int kv = 0; kv < 2; ++kv)
        for (int mt = 0; mt < 2; ++mt)
            for (int s = 0; s < 2; ++s) {
                int row = 128 + kv * 128 + h * 32 + mt * 16 + l15;
                const float* wp = wqkv + row * 64 + s * 32 + l4 * 8;
                s16x8 a;
#pragma unroll
                for (int j = 0; j < 8; ++j) a[j] = (short)f2bf(wp[j]);
                afr[kv][mt][s] = a;
            }

    f32x4 sacc[2][2] = {};
    float zrow[8] = {};

    unsigned short (*EK)[40] = EKV[wv][0];
    unsigned short (*EV)[40] = EKV[wv][1];
    const float* xb = x + (size_t)b * 64 * NSP;

    // staging addresses for this thread (2 float4 per tile)
    const int c0 = tid >> 3;                        // p=0 row
    const int ng0 = (tid & 7) ^ (c0 & 7);
    const int c1 = (tid + 256) >> 3;                // p=1 row
    const int ng1 = ((tid + 256) & 7) ^ (c1 & 7);
    // swizzled XT column for each staged ushort4 (8B-aligned: col^16==byte^32)
    const int sc0 = (4 * ng0) ^ (c0 & 16);
    const int sc1 = (4 * ng1) ^ (c1 & 16);
    // gather column XOR: (row&16) with row=s*32+l4*8+j  ->  (l4>=2)*16
    const int cxor = (l4 & 2) << 3;

    float4 g0, g1;
    {   // preload tile 0
        const int n0 = tbase * 32;
        g0 = *(const float4*)(xb + (size_t)c0 * NSP + n0 + 4 * ng0);
        g1 = *(const float4*)(xb + (size_t)c1 * NSP + n0 + 4 * ng1);
    }

    for (int it = 0; it < 6; ++it) {
        if (it > 0) __syncthreads();  // all waves done READING XT from iter-1
        // write staged regs -> XT (swizzled layout)
        {
            ushort4 u0, u1;
            u0.x = f2bf(g0.x); u0.y = f2bf(g0.y); u0.z = f2bf(g0.z); u0.w = f2bf(g0.w);
            u1.x = f2bf(g1.x); u1.y = f2bf(g1.y); u1.z = f2bf(g1.z); u1.w = f2bf(g1.w);
            *(ushort4*)&XT[c0][sc0] = u0;
            *(ushort4*)&XT[c1][sc1] = u1;
        }
        // issue next tile's loads; they land during this iter's compute
        if (it < 5) {
            const int n0 = (tbase + it + 1) * 32;
            g0 = *(const float4*)(xb + (size_t)c0 * NSP + n0 + 4 * ng0);
            g1 = *(const float4*)(xb + (size_t)c1 * NSP + n0 + 4 * ng1);
        }
        __syncthreads();              // XT writes visible

        // GEMM1: [K_h;V_h] = W @ xtile (M=64,K=64,N=32)
        f32x4 ck[2][2] = {}, cv[2][2] = {};
#pragma unroll
        for (int s = 0; s < 2; ++s)
#pragma unroll
            for (int nt = 0; nt < 2; ++nt) {
                const int col = (nt * 16 + l15) ^ cxor;   // unswizzle
                s16x8 bfr;  // B[k=c][n]: n=l15, c=l4*8+j (+32s)
#pragma unroll
                for (int j = 0; j < 8; ++j)
                    bfr[j] = (short)XT[s * 32 + l4 * 8 + j][col];
#pragma unroll
                for (int mt = 0; mt < 2; ++mt) {
                    ck[mt][nt] = MFMA(afr[0][mt][s], bfr, ck[mt][nt]);
                    cv[mt][nt] = MFMA(afr[1][mt][s], bfr, cv[mt][nt]);
                }
            }
        // exp -> Z(regs) + EK; V -> EV   (C: row=mt*16+l4*4+r, col=nt*16+l15)
#pragma unroll
        for (int mt = 0; mt < 2; ++mt)
#pragma unroll
            for (int nt = 0; nt < 2; ++nt) {
                int col = nt * 16 + l15;
#pragma unroll
                for (int r = 0; r < 4; ++r) {
                    int row = mt * 16 + l4 * 4 + r;
                    float ek = __expf(ck[mt][nt][r]);
                    zrow[mt * 4 + r] += ek;
                    EK[row][col] = f2bf(ek);
                    EV[row][col] = f2bf(cv[mt][nt][r]);
                }
            }
        // GEMM2: S_h += expK(32x32) @ V^T (wave-private, in-order DS pipe)
#pragma unroll
        for (int td = 0; td < 2; ++td) {
            s16x8 a2 = *(const s16x8*)&EK[td * 16 + l15][l4 * 8];
#pragma unroll
            for (int te = 0; te < 2; ++te) {
                s16x8 b2 = *(const s16x8*)&EV[te * 16 + l15][l4 * 8];
                sacc[td][te] = MFMA(a2, b2, sacc[td][te]);
            }
        }
    }

    // Z: butterfly over the 16 replicating l15 lanes
#pragma unroll
    for (int i = 0; i < 8; ++i) {
        float z = zrow[i];
        z += __shfl_xor(z, 1);
        z += __shfl_xor(z, 2);
        z += __shfl_xor(z, 4);
        z += __shfl_xor(z, 8);
        zrow[i] = z;
    }

    if (mode == 0) {
        // per-block partial: plain stores, fully written, no zeroing needed
        float* Zb = Zdst + (size_t)blk * 128;
        if (l15 == 0)
#pragma unroll
            for (int mt = 0; mt < 2; ++mt)
#pragma unroll
                for (int r = 0; r < 4; ++r)
                    Zb[h * 32 + mt * 16 + l4 * 4 + r] = zrow[mt * 4 + r];
        float* Sb = Sdst + (size_t)blk * 4096 + h * 1024;
#pragma unroll
        for (int td = 0; td < 2; ++td)
#pragma unroll
            for (int te = 0; te < 2; ++te)
#pragma unroll
                for (int r = 0; r < 4; ++r)
                    Sb[(td * 16 + l4 * 4 + r) * 32 + te * 16 + l15] =
                        sacc[td][te][r];
    } else {
        const int shadow = blk & (NSHADOW - 1);
        float* Zb = Zdst + (size_t)(shadow * 2 + b) * 128;
        if (l15 == 0)
#pragma unroll
            for (int mt = 0; mt < 2; ++mt)
#pragma unroll
                for (int r = 0; r < 4; ++r)
                    atomicAdd(&Zb[h * 32 + mt * 16 + l4 * 4 + r], zrow[mt * 4 + r]);
        float* Sb = Sdst + (size_t)(shadow * 2 + b) * 4096 + h * 1024;
#pragma unroll
        for (int td = 0; td < 2; ++td)
#pragma unroll
            for (int te = 0; te < 2; ++te)
#pragma unroll
                for (int r = 0; r < 4; ++r)
                    atomicAdd(&Sb[(td * 16 + l4 * 4 + r) * 32 + te * 16 + l15],
                              sacc[td][te][r]);
    }
}

// ---------------------------------------------------------------------------
// k2pre: 512 blocks (16 groups x 2 batches x 16 slice) x 64 threads (1 wave):
// sum 36 per-block partials (w = s + 16j) -> 16-intermediate layout.
// ---------------------------------------------------------------------------
__global__ __launch_bounds__(64) void k2pre(
    const float* __restrict__ Sp, const float* __restrict__ Zp,
    float* __restrict__ Ssh, float* __restrict__ Zsh)
{
    const int q = blockIdx.x & 15;
    const int b = (blockIdx.x >> 4) & 1;
    const int s = blockIdx.x >> 5;
    const int t = threadIdx.x;
    const int i = q * 256 + t * 4;
    float4 acc = {0.f, 0.f, 0.f, 0.f};
#pragma unroll 6
    for (int j = 0; j < 36; ++j) {
        const float4 v =
            *(const float4*)&Sp[(size_t)(b * 576 + s + 16 * j) * 4096 + i];
        acc.x += v.x; acc.y += v.y; acc.z += v.z; acc.w += v.w;
    }
    *(float4*)&Ssh[(size_t)(s * 2 + b) * 4096 + i] = acc;
    if (q == 0) {
        for (int e = t; e < 128; e += 64) {
            float z = 0.f;
#pragma unroll 6
            for (int j = 0; j < 36; ++j)
                z += Zp[(size_t)(b * 576 + s + 16 * j) * 128 + e];
            Zsh[(size_t)(s * 2 + b) * 128 + e] = z;
        }
    }
}

// ---------------------------------------------------------------------------
// k2a: 8 blocks (2 batches x 4 heads) x 256 threads: sum 16 shadows ->
// ctx[b][h][d][e] = S/Z, written to ws. Same summation order as old k2s.
// ---------------------------------------------------------------------------
__global__ __launch_bounds__(256) void k2a(
    const float* __restrict__ Ssh, const float* __restrict__ Zsh,
    float* __restrict__ ctxg)
{
    __shared__ float Zl[32];
    const int b = blockIdx.x & 1;
    const int h = blockIdx.x >> 1;
    const int t = threadIdx.x;
    if (t < 32) {
        float z = 0.f;
#pragma unroll
        for (int s = 0; s < NSHADOW; ++s)
            z += Zsh[(size_t)(s * 2 + b) * 128 + h * 32 + t];
        Zl[t] = z;
    }
    __syncthreads();
    const int li = t * 4;           // 4 consecutive e, same d
    const int d = li >> 5;
    float4 sv = {0.f, 0.f, 0.f, 0.f};
#pragma unroll
    for (int s = 0; s < NSHADOW; ++s) {
        const float4 v = *(const float4*)&Ssh[(size_t)(s * 2 + b) * 4096 + h * 1024 + li];
        sv.x += v.x; sv.y += v.y; sv.z += v.z; sv.w += v.w;
    }
    const float zi = Zl[d];
    sv.x /= zi; sv.y /= zi; sv.z /= zi; sv.w /= zi;
    *(float4*)&ctxg[(size_t)(b * 4 + h) * 1024 + li] = sv;
}

// ---------------------------------------------------------------------------
// k2b: 128 blocks (2 batches x 64 c) x 128 threads: P[hd=t] = wout[c] . ctx,
// LDS, then t<64: WE[c][c2=t] = P . wqkv[:,c2]. Same loop orders as old k2s.
// ---------------------------------------------------------------------------
__global__ __launch_bounds__(128) void k2b(
    const float* __restrict__ ctxg, const float* __restrict__ wout,
    const float* __restrict__ wqkv, unsigned short* __restrict__ WE)
{
    __shared__ float P[128];
    const int b = blockIdx.x >> 6;
    const int c = blockIdx.x & 63;
    const int t = threadIdx.x;
    {   // P[c][hd] for hd = t
        const int h = t >> 5, d = t & 31;
        const float* wo = wout + c * 128 + h * 32;
        const float* cx = ctxg + (size_t)(b * 4 + h) * 1024 + d * 32;
        float acc = 0.f;
#pragma unroll 8
        for (int e = 0; e < 32; ++e) acc += wo[e] * cx[e];
        P[t] = acc;
    }
    __syncthreads();
    if (t < 64) {
        float acc = 0.f;
#pragma unroll 8
        for (int hd = 0; hd < 128; ++hd) acc += P[hd] * wqkv[hd * 64 + t];
        WE[b * 4096 + c * 64 + t] = f2bf(acc);
    }
}

// ---------------------------------------------------------------------------
// k2s (fallback path only): original 2-block kernel.
// ---------------------------------------------------------------------------
__global__ __launch_bounds__(1024) void k2s(
    const float* __restrict__ Ssh, const float* __restrict__ Zsh,
    const float* __restrict__ wout, const float* __restrict__ wqkv,
    unsigned short* __restrict__ WE)
{
    __shared__ float ctx[4][32][32];
    __shared__ float P[64][128];
    __shared__ float Zl[128];
    const int b = blockIdx.x;
    const int t = threadIdx.x;
    if (t < 128) {
        float z = 0.f;
#pragma unroll
        for (int s = 0; s < NSHADOW; ++s) z += Zsh[(size_t)(s * 2 + b) * 128 + t];
        Zl[t] = z;
    }
    __syncthreads();
    for (int i = t; i < 4096; i += 1024) {
        float sv = 0.f;
#pragma unroll
        for (int s = 0; s < NSHADOW; ++s) sv += Ssh[(size_t)(s * 2 + b) * 4096 + i];
        int h = i >> 10, d = (i >> 5) & 31;
        ctx[h][d][i & 31] = sv / Zl[h * 32 + d];
    }
    __syncthreads();
    for (int i = t; i < 8192; i += 1024) {
        int c = i >> 7, hd = i & 127, h = hd >> 5, d = hd & 31;
        const float* wo = wout + c * 128 + h * 32;
        float acc = 0.f;
#pragma unroll 8
        for (int e = 0; e < 32; ++e) acc += wo[e] * ctx[h][d][e];
        P[c][hd] = acc;
    }
    __syncthreads();
    for (int i = t; i < 4096; i += 1024) {
        int c = i >> 6, c2 = i & 63;
        float acc = 0.f;
#pragma unroll 8
        for (int hd = 0; hd < 128; ++hd) acc += P[c][hd] * wqkv[hd * 64 + c2];
        WE[b * 4096 + c * 64 + c2] = f2bf(acc);
    }
}

// ---------------------------------------------------------------------------
// k3e: out[b] = Weff[b]@x[b] + bias. 1728 blocks x 128-col strips. LDS-FREE:
// per-wave disjoint 32-col slab; B-frags straight from global (4x64B
// segments/instr, x read once/block), f2bf in regs, MFMA, direct stores.
// ---------------------------------------------------------------------------
__global__ __launch_bounds__(256) void k3e(
    const float* __restrict__ x, const unsigned short* __restrict__ WE,
    const float* __restrict__ bout, float* __restrict__ out)
{
    const int tid = threadIdx.x;
    const int wv = tid >> 6;
    const int l = tid & 63;
    const int l15 = l & 15, l4 = l >> 4;
    const int b = blockIdx.x / 864;
    const int n0 = (blockIdx.x % 864) * 128;

    s16x8 afr[4][2];
#pragma unroll
    for (int mt = 0; mt < 4; ++mt)
#pragma unroll
        for (int s = 0; s < 2; ++s)
            afr[mt][s] = *(const s16x8*)(WE + b * 4096 + (mt * 16 + l15) * 64 + s * 32 + l4 * 8);

    float bias[4][4];
#pragma unroll
    for (int mt = 0; mt < 4; ++mt)
#pragma unroll
        for (int r = 0; r < 4; ++r) bias[mt][r] = bout[mt * 16 + l4 * 4 + r];

    const float* xb = x + (size_t)b * 64 * NSP;
    float* ob = out + (size_t)b * 64 * NSP;

    const int nq = wv * 32;
    const float* xq = xb + (size_t)(l4 * 8) * NSP + n0 + nq + l15;

    f32x4 acc[4][2] = {};
#pragma unroll
    for (int s = 0; s < 2; ++s) {
        float t0[8], t1[8];
#pragma unroll
        for (int j = 0; j < 8; ++j) {
            const float* p = xq + (size_t)(s * 32 + j) * NSP;
            t0[j] = p[0];
            t1[j] = p[16];
        }
        s16x8 b0, b1;
#pragma unroll
        for (int j = 0; j < 8; ++j) {
            b0[j] = (short)f2bf(t0[j]);
            b1[j] = (short)f2bf(t1[j]);
        }
#pragma unroll
        for (int mt = 0; mt < 4; ++mt) {
            acc[mt][0] = MFMA(afr[mt][s], b0, acc[mt][0]);
            acc[mt][1] = MFMA(afr[mt][s], b1, acc[mt][1]);
        }
    }

#pragma unroll
    for (int mt = 0; mt < 4; ++mt)
#pragma unroll
        for (int nt = 0; nt < 2; ++nt)
#pragma unroll
            for (int r = 0; r < 4; ++r)
                ob[(size_t)(mt * 16 + l4 * 4 + r) * NSP + n0 + nq + nt * 16 + l15] =
                    acc[mt][nt][r] + bias[mt][r];
}

extern "C" void kernel_launch(void* const* d_in, const int* in_sizes, int n_in,
                              void* d_out, int out_size, void* d_ws, size_t ws_size,
                              hipStream_t stream) {
    // Inputs by size (order-proof): x=14155776, w_qkv=24576, w_out=8192, b_out=64.
    const float *x = nullptr, *wqkv = nullptr, *wout = nullptr, *bout = nullptr;
    for (int i = 0; i < n_in; ++i) {
        if (in_sizes[i] == 2 * 64 * NSP) x = (const float*)d_in[i];
        else if (in_sizes[i] == 384 * 64) wqkv = (const float*)d_in[i];
        else if (in_sizes[i] == 64 * 128) wout = (const float*)d_in[i];
        else if (in_sizes[i] == 64) bout = (const float*)d_in[i];
    }
    if (!x) x = (const float*)d_in[0];
    if (!wqkv) wqkv = (const float*)d_in[1];
    if (!wout) wout = (const float*)d_in[2];
    if (!bout) bout = (const float*)d_in[3];
    float* out = (float*)d_out;

    // big path layout:
    //   Sp fp32[1152][4096]   @0              (18874368 B)
    //   Zp fp32[1152][128]    @18874368       (589824 B)
    //   Ssh fp32[16][2][4096] @19464192       (524288 B)
    //   Zsh fp32[16][2][128]  @19988480       (16384 B)
    //   WE bf16[2][4096]      @20004864       (16384 B)
    //   ctx fp32[2][4][1024]  @20021248       (32768 B)   end: 20054016
    // small path (fallback): Ssh @0, Zsh @524288, WE @540672 (atomics)
    const size_t NEED_BIG = 20054016;
    if (ws_size >= NEED_BIG) {
        float* Sp = (float*)d_ws;
        float* Zp = (float*)((char*)d_ws + 18874368);
        float* Ssh = (float*)((char*)d_ws + 19464192);
        float* Zsh = (float*)((char*)d_ws + 19988480);
        unsigned short* WE = (unsigned short*)((char*)d_ws + 20004864);
        float* ctxg = (float*)((char*)d_ws + 20021248);
        hipLaunchKernelGGL(k1z, dim3(1152), dim3(256), 0, stream, x, wqkv, Sp, Zp, 0);
        hipLaunchKernelGGL(k2pre, dim3(512), dim3(64), 0, stream, Sp, Zp, Ssh, Zsh);
        hipLaunchKernelGGL(k2a, dim3(8), dim3(256), 0, stream, Ssh, Zsh, ctxg);
        hipLaunchKernelGGL(k2b, dim3(128), dim3(128), 0, stream, ctxg, wout, wqkv, WE);
        hipLaunchKernelGGL(k3e, dim3(1728), dim3(256), 0, stream, x, WE, bout, out);
    } else {
        float* Ssh = (float*)d_ws;
        float* Zsh = (float*)((char*)d_ws + 524288);
        unsigned short* WE = (unsigned short*)((char*)d_ws + 540672);
        hipMemsetAsync(d_ws, 0, 540672, stream);  // zero shadows
        hipLaunchKernelGGL(k1z, dim3(1152), dim3(256), 0, stream, x, wqkv, Ssh, Zsh, 1);
        hipLaunchKernelGGL(k2s, dim3(2), dim3(1024), 0, stream, Ssh, Zsh, wout, wqkv, WE);
        hipLaunchKernelGGL(k3e, dim3(1728), dim3(256), 0, stream, x, WE, bout, out);
    }
}